// Round 19
// baseline (183.369 us; speedup 1.0000x reference)
//
#include <hip/hip_runtime.h>
#include <hip/hip_bf16.h>
#include <cstdint>
#include <cstddef>

#define NPATCH 50000
#define GC 256

typedef __bf16 bf16x8 __attribute__((ext_vector_type(8)));
typedef float  f32x4  __attribute__((ext_vector_type(4)));
typedef float  f32x8  __attribute__((ext_vector_type(8)));

// ---------------- workspace layout (bytes) ----------------
static constexpr size_t XB_OFF    = 0;                         // bf16 x [50048][512]
static constexpr size_t XB_BYTES  = (size_t)50048 * 512 * 2;
static constexpr size_t W1B_OFF   = XB_OFF + XB_BYTES;         // bf16 W1 [512][1024]
static constexpr size_t W1B_BYTES = (size_t)512 * 1024 * 2;
static constexpr size_t W2AB_OFF  = W1B_OFF + W1B_BYTES;       // bf16 W2a [256][512]
static constexpr size_t W2X_BYTES = (size_t)256 * 512 * 2;
static constexpr size_t W2BB_OFF  = W2AB_OFF + W2X_BYTES;      // bf16 W2b [256][512]
static constexpr size_t MUG_OFF   = W2BB_OFF + W2X_BYTES;      // f32 [65536]
static constexpr size_t LVG_OFF   = MUG_OFF + (size_t)65536 * 4;
static constexpr size_t AG_OFF    = LVG_OFF + (size_t)65536 * 4;
static constexpr size_t MPART_OFF = AG_OFF + (size_t)65536 * 4; // f32 [512] (legacy, unused)
static constexpr size_t SUMA_OFF  = MPART_OFF + (size_t)512 * 4;
static constexpr size_t ZERO_BYTES = SUMA_OFF + 4 - MUG_OFF;   // zero mug..sumA
static constexpr int    ZERO_F32   = (int)(ZERO_BYTES / 4);    // 197121 floats
static constexpr size_t MPART2_OFF = ((SUMA_OFF + 4 + 63) / 64) * 64; // f32 [392][512]
static constexpr size_t SUMAP_OFF  = MPART2_OFF + (size_t)392 * 512 * 4; // f32 [392]

__device__ __forceinline__ unsigned short f2bf(float f) {
  union { float f; uint32_t u; } v; v.f = f;
  uint32_t u = v.u;
  uint32_t r = (u + 0x7FFFu + ((u >> 16) & 1u)) >> 16;
  return (unsigned short)r;
}
__device__ __forceinline__ float bf2f(uint32_t bits16) {
  union { uint32_t u; float f; } v; v.u = bits16 << 16; return v.f;
}
__device__ __forceinline__ unsigned short cvt_bf16(float f) {
  __bf16 b = (__bf16)f;
  return __builtin_bit_cast(unsigned short, b);
}
__device__ __forceinline__ void gld16(const void* g, void* l) {
  __builtin_amdgcn_global_load_lds(
      (const __attribute__((address_space(1))) void*)g,
      (__attribute__((address_space(3))) void*)l, 16, 0, 0);
}
__device__ __forceinline__ bf16x8 cvt8(const float4& f0, const float4& f1) {
  f32x8 fv;
  fv[0]=f0.x; fv[1]=f0.y; fv[2]=f0.z; fv[3]=f0.w;
  fv[4]=f1.x; fv[5]=f1.y; fv[6]=f1.z; fv[7]=f1.w;
  return __builtin_convertvector(fv, bf16x8);
}

// ---------------- K0: convert weights f32 -> bf16 + zero ws region ----------------
__global__ void convert_weights(const float* __restrict__ W1,
                                const float* __restrict__ W2a,
                                const float* __restrict__ W2b,
                                unsigned short* __restrict__ W1b,
                                unsigned short* __restrict__ W2ab,
                                unsigned short* __restrict__ W2bb,
                                float* __restrict__ zws) {
  int i = blockIdx.x * 256 + threadIdx.x;
  if (i < 512 * 1024) W1b[i] = f2bf(W1[i]);
  if (i < 256 * 512) { W2ab[i] = f2bf(W2a[i]); W2bb[i] = f2bf(W2b[i]); }
  if (i < ZERO_F32) zws[i] = 0.f;   // mug, lvg, Ag, (legacy Mpart/sumA)
}

// ---------------- K1: x = relu(h @ W1^T + b1) -> bf16 ----------------
// (R16/R18-exact, measured best) 256x256 tile, BK=32, 512 threads = 8 waves
// (2M x 4N), per-wave 128x64 (acc[8][4]). P0: frag reads + A ds_write(t+1)
// + A-loads(t+2); P1: frag reads + B-gld16(t+2). Counted vmcnt(6) boundary;
// swizzled LDS (0 conflicts); bijective XCD remap.
__global__ __launch_bounds__(512, 2) void gemm1(
    const float* __restrict__ h, const unsigned short* __restrict__ W1b,
    const float* __restrict__ b1, unsigned short* __restrict__ xb) {
  __shared__ __align__(16) unsigned short lds[40960];  // 80 KB
  unsigned short* const A0 = lds;
  unsigned short* const A1 = lds + 8192;
  unsigned short* const B0 = lds + 16384;
  unsigned short* const B1 = lds + 24576;
  unsigned short* const B2 = lds + 32768;

  const int t  = threadIdx.x;
  const int l  = t & 63;
  const int w  = t >> 6;
  const int wm = w >> 2;
  const int wn = w & 3;
  const int g  = l >> 4;
  const int lr = l & 15;

  const int i   = blockIdx.x;
  const int xcd = i & 7;
  const int pos = i >> 3;
  const int v   = xcd * 49 + pos;
  const int rt  = v >> 1;
  const int ct  = v & 1;
  const int rowBase = rt * 256;
  const int colBase = ct * 256;

  const int tr = t >> 1;
  const int hh = t & 1;
  int gr = rowBase + tr; if (gr >= NPATCH) gr = NPATCH - 1;
  const float* ah = h + (size_t)gr * 1024 + hh * 16;
  const int sw  = (tr >> 1) & 3;
  const int aw0 = tr * 32 + ((hh * 2)     ^ sw) * 8;
  const int aw1 = tr * 32 + ((hh * 2 + 1) ^ sw) * 8;

  const int bj = (t & 3) ^ ((t >> 3) & 3);
  const unsigned short* bh  = W1b + (size_t)(colBase + (t >> 2)) * 1024 + bj * 8;
  const unsigned short* bh2 = bh + (size_t)128 * 1024;
  const int bd0 = t * 8;
  const int bd1 = 4096 + t * 8;

  const int rs = (g ^ ((lr >> 1) & 3)) * 8;
  const int abase = (wm * 128 + lr) * 32 + rs;
  const int bbase = (wn * 64 + lr) * 32 + rs;

  f32x4 acc[8][4];
#pragma unroll
  for (int m = 0; m < 8; ++m)
#pragma unroll
    for (int n = 0; n < 4; ++n) acc[m][n] = (f32x4){0.f, 0.f, 0.f, 0.f};

  unsigned short *pAr = A0, *pAw = A1;
  unsigned short *pBr = B0, *pBr1 = B1, *pBw = B2;

  float4 q0, q1, q2, q3;
  {
    gld16(bh, pBr + bd0); gld16(bh2, pBr + bd1);
    float4 f0 = *(const float4*)(ah + 0);
    float4 f1 = *(const float4*)(ah + 4);
    float4 f2 = *(const float4*)(ah + 8);
    float4 f3 = *(const float4*)(ah + 12);
    *(bf16x8*)(pAr + aw0) = cvt8(f0, f1);
    *(bf16x8*)(pAr + aw1) = cvt8(f2, f3);
    q0 = *(const float4*)(ah + 32);
    q1 = *(const float4*)(ah + 36);
    q2 = *(const float4*)(ah + 40);
    q3 = *(const float4*)(ah + 44);
    gld16(bh + 32, pBr1 + bd0); gld16(bh2 + 32, pBr1 + bd1);
  }
  asm volatile("s_waitcnt lgkmcnt(0)\n\ts_barrier" ::: "memory");

  for (int kt = 0; kt < 32; ++kt) {
    const int ka = ((kt + 2 <= 31) ? (kt + 2) : 31) * 32;
    bf16x8 af[4], bf[4];
#pragma unroll
    for (int m = 0; m < 4; ++m)
      af[m] = *(const bf16x8*)(pAr + abase + m * 512);
#pragma unroll
    for (int n = 0; n < 4; ++n)
      bf[n] = *(const bf16x8*)(pBr + bbase + n * 512);
    *(bf16x8*)(pAw + aw0) = cvt8(q0, q1);
    *(bf16x8*)(pAw + aw1) = cvt8(q2, q3);
    q0 = *(const float4*)(ah + ka + 0);
    q1 = *(const float4*)(ah + ka + 4);
    q2 = *(const float4*)(ah + ka + 8);
    q3 = *(const float4*)(ah + ka + 12);
    __builtin_amdgcn_sched_barrier(0);
    __builtin_amdgcn_s_barrier();
    __builtin_amdgcn_s_setprio(1);
#pragma unroll
    for (int m = 0; m < 4; ++m)
#pragma unroll
      for (int n = 0; n < 4; ++n)
        acc[m][n] = __builtin_amdgcn_mfma_f32_16x16x32_bf16(af[m], bf[n], acc[m][n], 0, 0, 0);
    __builtin_amdgcn_s_setprio(0);
    __builtin_amdgcn_s_barrier();
#pragma unroll
    for (int m = 0; m < 4; ++m)
      af[m] = *(const bf16x8*)(pAr + abase + (m + 4) * 512);
    gld16(bh + ka, pBw + bd0);
    gld16(bh2 + ka, pBw + bd1);
    __builtin_amdgcn_sched_barrier(0);
    __builtin_amdgcn_s_barrier();
    __builtin_amdgcn_s_setprio(1);
#pragma unroll
    for (int m = 0; m < 4; ++m)
#pragma unroll
      for (int n = 0; n < 4; ++n)
        acc[m + 4][n] = __builtin_amdgcn_mfma_f32_16x16x32_bf16(af[m], bf[n], acc[m + 4][n], 0, 0, 0);
    __builtin_amdgcn_s_setprio(0);
    asm volatile("s_waitcnt vmcnt(6) lgkmcnt(0)\n\ts_barrier" ::: "memory");
    unsigned short* tA = pAr; pAr = pAw; pAw = tA;
    unsigned short* tB = pBr; pBr = pBr1; pBr1 = pBw; pBw = tB;
  }
  asm volatile("s_waitcnt vmcnt(0) lgkmcnt(0)" ::: "memory");

  float b1v[4];
#pragma unroll
  for (int n = 0; n < 4; ++n) b1v[n] = b1[colBase + wn * 64 + n * 16 + lr];
#pragma unroll
  for (int m = 0; m < 8; ++m) {
    const int rb0 = rowBase + wm * 128 + m * 16 + g * 4;
#pragma unroll
    for (int r = 0; r < 4; ++r) {
      const int row = rb0 + r;
      if (row < NPATCH) {
        unsigned short* xrow = xb + (size_t)row * 512 + colBase + wn * 64;
#pragma unroll
        for (int n = 0; n < 4; ++n) {
          float vv = acc[m][n][r] + b1v[n];
          vv = vv > 0.f ? vv : 0.f;
          xrow[n * 16 + lr] = cvt_bf16(vv);
        }
      }
    }
  }
}

// ---------------- K2: fa=sig(x@W2a^T+b2a), fb=tanh(x@W2b^T+b2b),
//                      params=(fa*fb)@W3^T+b3, scatter mu/logvar ----------------
// (R14 version) 128x256 tile, 8 waves, all operands via gld16, swizzled
// frag reads, dbuf + one __syncthreads/K-step.
__global__ __launch_bounds__(512) void gemm2(
    const unsigned short* __restrict__ xb,
    const unsigned short* __restrict__ W2ab, const unsigned short* __restrict__ W2bb,
    const float* __restrict__ b2a, const float* __restrict__ b2b,
    const float* __restrict__ W3, const float* __restrict__ b3,
    const int* __restrict__ coords,
    float* __restrict__ mug, float* __restrict__ lvg) {
  __shared__ __align__(16) unsigned short xs[2][128 * 32];   // 16 KB
  __shared__ __align__(16) unsigned short was[2][256 * 32];  // 32 KB
  __shared__ __align__(16) unsigned short wbs[2][256 * 32];  // 32 KB
  __shared__ float pmu_s[4][128];
  __shared__ float plv_s[4][128];

  const int t  = threadIdx.x;
  const int l  = t & 63;
  const int w  = t >> 6;        // 0..7
  const int wm = w >> 2;        // 0..1 (row half: 64 rows)
  const int wn = w & 3;         // 0..3 (col quarter: 64 cols)
  const int g  = l >> 4;
  const int lr = l & 15;
  const int rowBase = blockIdx.x * 128;

  const int bj = (t & 3) ^ ((t >> 3) & 3);
  const unsigned short* xsrc   = xb   + (size_t)(rowBase + (t >> 2)) * 512 + bj * 8;
  const unsigned short* wasrc0 = W2ab + (size_t)(t >> 2) * 512 + bj * 8;
  const unsigned short* wasrc1 = wasrc0 + (size_t)128 * 512;
  const unsigned short* wbsrc0 = W2bb + (size_t)(t >> 2) * 512 + bj * 8;
  const unsigned short* wbsrc1 = wbsrc0 + (size_t)128 * 512;
  const int d0 = t * 8;
  const int d1 = 4096 + t * 8;

  const int rslot = (g ^ ((lr >> 1) & 3)) * 8;

  f32x4 aa[4][4], ab[4][4];
#pragma unroll
  for (int m = 0; m < 4; ++m)
#pragma unroll
    for (int n = 0; n < 4; ++n) {
      aa[m][n] = (f32x4){0.f, 0.f, 0.f, 0.f};
      ab[m][n] = (f32x4){0.f, 0.f, 0.f, 0.f};
    }

  {
    gld16(xsrc,   &xs[0][d0]);
    gld16(wasrc0, &was[0][d0]);
    gld16(wasrc1, &was[0][d1]);
    gld16(wbsrc0, &wbs[0][d0]);
    gld16(wbsrc1, &wbs[0][d1]);
  }
  __syncthreads();

  int cur = 0;
  for (int kt = 0; kt < 16; ++kt) {
    if (kt < 15) {
      const int k0 = (kt + 1) * 32;
      gld16(xsrc + k0,   &xs[cur ^ 1][d0]);
      gld16(wasrc0 + k0, &was[cur ^ 1][d0]);
      gld16(wasrc1 + k0, &was[cur ^ 1][d1]);
      gld16(wbsrc0 + k0, &wbs[cur ^ 1][d0]);
      gld16(wbsrc1 + k0, &wbs[cur ^ 1][d1]);
    }
    bf16x8 af[4], ba[4], bb[4];
#pragma unroll
    for (int m = 0; m < 4; ++m)
      af[m] = *(const bf16x8*)&xs[cur][(wm * 64 + m * 16 + lr) * 32 + rslot];
#pragma unroll
    for (int n = 0; n < 4; ++n) {
      const int brow = (wn * 64 + n * 16 + lr) * 32 + rslot;
      ba[n] = *(const bf16x8*)&was[cur][brow];
      bb[n] = *(const bf16x8*)&wbs[cur][brow];
    }
#pragma unroll
    for (int m = 0; m < 4; ++m)
#pragma unroll
      for (int n = 0; n < 4; ++n) {
        aa[m][n] = __builtin_amdgcn_mfma_f32_16x16x32_bf16(af[m], ba[n], aa[m][n], 0, 0, 0);
        ab[m][n] = __builtin_amdgcn_mfma_f32_16x16x32_bf16(af[m], bb[n], ab[m][n], 0, 0, 0);
      }
    __syncthreads();
    cur ^= 1;
  }

  float b2av[4], b2bv[4], w30v[4], w31v[4];
#pragma unroll
  for (int n = 0; n < 4; ++n) {
    const int col = wn * 64 + n * 16 + lr;
    b2av[n] = b2a[col]; b2bv[n] = b2b[col];
    w30v[n] = W3[col];  w31v[n] = W3[256 + col];
  }
#pragma unroll
  for (int m = 0; m < 4; ++m) {
#pragma unroll
    for (int r = 0; r < 4; ++r) {
      float pm = 0.f, pl = 0.f;
#pragma unroll
      for (int n = 0; n < 4; ++n) {
        float a = 1.f / (1.f + __expf(-(aa[m][n][r] + b2av[n])));
        float b = tanhf(ab[m][n][r] + b2bv[n]);
        float p = a * b;
        pm += p * w30v[n];
        pl += p * w31v[n];
      }
#pragma unroll
      for (int d = 1; d < 16; d <<= 1) {
        pm += __shfl_xor(pm, d, 64);
        pl += __shfl_xor(pl, d, 64);
      }
      if (lr == 0) {
        pmu_s[wn][wm * 64 + m * 16 + g * 4 + r] = pm;
        plv_s[wn][wm * 64 + m * 16 + g * 4 + r] = pl;
      }
    }
  }
  __syncthreads();
  if (t < 128) {
    float mu = pmu_s[0][t] + pmu_s[1][t] + pmu_s[2][t] + pmu_s[3][t] + b3[0];
    float lv = plv_s[0][t] + plv_s[1][t] + plv_s[2][t] + plv_s[3][t] + b3[1];
    int row = rowBase + t;
    if (row < NPATCH) {
      int gx = coords[2 * row] >> 8;
      int gy = coords[2 * row + 1] >> 8;
      int cell = gy * GC + gx;
      mug[cell] = mu;
      lvg[cell] = lv;
    }
  }
}

// ---------------- K3: kl_div, 3x3 conv, reparam, sigmoid -> A grid ----------------
__global__ void grid_ops(const float* __restrict__ mug, const float* __restrict__ lvg,
                         const float* __restrict__ eps, const float* __restrict__ kern,
                         const int* __restrict__ slide, float* __restrict__ Ag,
                         float* __restrict__ out_kl) {
  int cell = blockIdx.x * 256 + threadIdx.x;
  int iy = cell >> 8, ix = cell & 255;
  float mu = mug[cell], lv = lvg[cell];
  int sl = slide[0];
  float pm  = (sl == 0) ? -5.0f : 0.0f;
  float plv = (sl == 0) ? -1.0f : 3.0f;
  float d = pm - mu;
  out_kl[cell] = (plv - lv) * 0.5f + (lv * lv + d * d) / (2.0f * plv * plv) - 0.5f;
  float s = 0.f;
#pragma unroll
  for (int dy = 0; dy < 3; ++dy) {
#pragma unroll
    for (int dx = 0; dx < 3; ++dx) {
      int y = iy + dy - 1, x = ix + dx - 1;
      if (y >= 0 && y < GC && x >= 0 && x < GC)
        s += mug[y * GC + x] * kern[dy * 3 + dx];
    }
  }
  float sample = s + eps[cell] * __expf(0.5f * lv);
  Ag[cell] = 1.f / (1.f + __expf(-sample));
}

// ---------------- K4: gather patch_A, per-block partial sums (NO atomics) ----------------
// 392 blocks x 128 rows, 256 threads; thread t owns cols 2t,2t+1 via one u32
// load per row; writes Mpart2[block][512] + sumAp[block] partials to ws.
__global__ __launch_bounds__(256) void patch_pass(
    const float* __restrict__ Ag, const int* __restrict__ coords,
    const unsigned short* __restrict__ xb, float* __restrict__ out_pA,
    float* __restrict__ Mpart2, float* __restrict__ sumAp) {
  __shared__ float als[128];
  __shared__ float sred[2];
  const int t = threadIdx.x;
  const int base = blockIdx.x * 128;

  if (t < 128) {
    const int row = base + t;
    float a = 0.f;
    if (row < NPATCH) {
      int gx = coords[2 * row] >> 8;
      int gy = coords[2 * row + 1] >> 8;
      a = Ag[gy * GC + gx];
      out_pA[row] = a;
    }
    als[t] = a;
    float sa = a;
#pragma unroll
    for (int d = 1; d < 64; d <<= 1) sa += __shfl_xor(sa, d, 64);
    if ((t & 63) == 0) sred[t >> 6] = sa;
  }
  __syncthreads();
  if (t == 0) sumAp[blockIdx.x] = sred[0] + sred[1];

  int nrows = NPATCH - base;
  if (nrows > 128) nrows = 128;
  if (nrows < 0) nrows = 0;
  float m0 = 0.f, m1 = 0.f;
  for (int r = 0; r < nrows; ++r) {
    const float av = als[r];
    const uint32_t v = *(const uint32_t*)(xb + (size_t)(base + r) * 512 + t * 2);
    m0 += av * bf2f(v & 0xFFFFu);
    m1 += av * bf2f(v >> 16);
  }
  Mpart2[(size_t)blockIdx.x * 512 + 2 * t]     = m0;
  Mpart2[(size_t)blockIdx.x * 512 + 2 * t + 1] = m1;
}

// ---------------- K5: cross-block reduce + logits, softmax, argmax ----------------
__global__ __launch_bounds__(256) void finalize(
    const float* __restrict__ Mpart2, const float* __restrict__ sumAp,
    const float* __restrict__ Wc, const float* __restrict__ bc,
    float* __restrict__ out) {
  __shared__ float red0[4], red1[4], reds[4];
  const int t = threadIdx.x;  // 256 threads; thread owns cols 2t, 2t+1
  const int c0 = 2 * t, c1 = 2 * t + 1;
  float m0 = 0.f, m1 = 0.f;
  for (int b = 0; b < 392; ++b) {
    m0 += Mpart2[(size_t)b * 512 + c0];
    m1 += Mpart2[(size_t)b * 512 + c1];
  }
  float sa = 0.f;
  if (t < 196) sa = sumAp[t] + ((t + 196 < 392) ? sumAp[t + 196] : 0.f);
#pragma unroll
  for (int d = 1; d < 64; d <<= 1) sa += __shfl_xor(sa, d, 64);
  if ((t & 63) == 0) reds[t >> 6] = sa;

  float l0 = m0 * Wc[c0] + m1 * Wc[c1];
  float l1 = m0 * Wc[512 + c0] + m1 * Wc[512 + c1];
#pragma unroll
  for (int d = 1; d < 64; d <<= 1) {
    l0 += __shfl_xor(l0, d, 64);
    l1 += __shfl_xor(l1, d, 64);
  }
  if ((t & 63) == 0) { red0[t >> 6] = l0; red1[t >> 6] = l1; }
  __syncthreads();
  if (t == 0) {
    const float s = reds[0] + reds[1] + reds[2] + reds[3];
    l0 = (red0[0] + red0[1] + red0[2] + red0[3]) / s + bc[0];
    l1 = (red1[0] + red1[1] + red1[2] + red1[3]) / s + bc[1];
    float mx = fmaxf(l0, l1);
    float e0 = __expf(l0 - mx), e1 = __expf(l1 - mx);
    float inv = 1.f / (e0 + e1);
    float p0 = e0 * inv, p1 = e1 * inv;
    out[0] = l0; out[1] = l1;            // top_instance
    out[2] = p0; out[3] = p1;            // Y_prob
    out[4] = (l1 > l0) ? 1.0f : 0.0f;    // Y_hat
    out[65541] = p0; out[65542] = p1;    // y_probs
  }
}

extern "C" void kernel_launch(void* const* d_in, const int* in_sizes, int n_in,
                              void* d_out, int out_size, void* d_ws, size_t ws_size,
                              hipStream_t stream) {
  const float* h      = (const float*)d_in[0];
  const int*   coords = (const int*)d_in[1];
  const float* eps    = (const float*)d_in[2];
  const float* W1     = (const float*)d_in[3];
  const float* b1     = (const float*)d_in[4];
  const float* W2a    = (const float*)d_in[5];
  const float* b2a    = (const float*)d_in[6];
  const float* W2b    = (const float*)d_in[7];
  const float* b2b    = (const float*)d_in[8];
  const float* W3     = (const float*)d_in[9];
  const float* b3     = (const float*)d_in[10];
  const float* Wc     = (const float*)d_in[11];
  const float* bc     = (const float*)d_in[12];
  const float* kern   = (const float*)d_in[13];
  const int*   slide  = (const int*)d_in[16];
  float* out = (float*)d_out;
  char*  ws  = (char*)d_ws;

  unsigned short* xb   = (unsigned short*)(ws + XB_OFF);
  unsigned short* W1b  = (unsigned short*)(ws + W1B_OFF);
  unsigned short* W2ab = (unsigned short*)(ws + W2AB_OFF);
  unsigned short* W2bb = (unsigned short*)(ws + W2BB_OFF);
  float* mug    = (float*)(ws + MUG_OFF);
  float* lvg    = (float*)(ws + LVG_OFF);
  float* Ag     = (float*)(ws + AG_OFF);
  float* Mpart2 = (float*)(ws + MPART2_OFF);
  float* sumAp  = (float*)(ws + SUMAP_OFF);

  convert_weights<<<2048, 256, 0, stream>>>(W1, W2a, W2b, W1b, W2ab, W2bb,
                                            (float*)(ws + MUG_OFF));
  gemm1<<<392, 512, 0, stream>>>(h, W1b, b1, xb);
  gemm2<<<391, 512, 0, stream>>>(xb, W2ab, W2bb, b2a, b2b, W3, b3, coords, mug, lvg);
  grid_ops<<<256, 256, 0, stream>>>(mug, lvg, eps, kern, slide, Ag, out + 5);
  patch_pass<<<392, 256, 0, stream>>>(Ag, coords, xb, out + 65543, Mpart2, sumAp);
  finalize<<<1, 256, 0, stream>>>(Mpart2, sumAp, Wc, bc, out);
}

// Round 20
// 183.039 us; speedup vs baseline: 1.0018x; 1.0018x over previous
//
#include <hip/hip_runtime.h>
#include <hip/hip_bf16.h>
#include <cstdint>
#include <cstddef>

#define NPATCH 50000
#define GC 256

typedef __bf16 bf16x8 __attribute__((ext_vector_type(8)));
typedef float  f32x4  __attribute__((ext_vector_type(4)));
typedef float  f32x8  __attribute__((ext_vector_type(8)));

// ---------------- workspace layout (bytes) ----------------
static constexpr size_t XB_OFF    = 0;                         // bf16 x [50048][512]
static constexpr size_t XB_BYTES  = (size_t)50048 * 512 * 2;
static constexpr size_t W1B_OFF   = XB_OFF + XB_BYTES;         // bf16 W1 [512][1024]
static constexpr size_t W1B_BYTES = (size_t)512 * 1024 * 2;
static constexpr size_t W2AB_OFF  = W1B_OFF + W1B_BYTES;       // bf16 W2a [256][512]
static constexpr size_t W2X_BYTES = (size_t)256 * 512 * 2;
static constexpr size_t W2BB_OFF  = W2AB_OFF + W2X_BYTES;      // bf16 W2b [256][512]
static constexpr size_t MUG_OFF   = W2BB_OFF + W2X_BYTES;      // f32 [65536]
static constexpr size_t LVG_OFF   = MUG_OFF + (size_t)65536 * 4;
static constexpr size_t AG_OFF    = LVG_OFF + (size_t)65536 * 4;  // (legacy, unused)
static constexpr size_t MPART_OFF = AG_OFF + (size_t)65536 * 4;   // (legacy, unused)
static constexpr size_t SUMA_OFF  = MPART_OFF + (size_t)512 * 4;
static constexpr size_t ZERO_BYTES = SUMA_OFF + 4 - MUG_OFF;   // zero mug..sumA
static constexpr int    ZERO_F32   = (int)(ZERO_BYTES / 4);    // 197121 floats
static constexpr size_t MPART2_OFF = ((SUMA_OFF + 4 + 63) / 64) * 64; // f32 [392][512]
static constexpr size_t SUMAP_OFF  = MPART2_OFF + (size_t)392 * 512 * 4; // f32 [392]

__device__ __forceinline__ unsigned short f2bf(float f) {
  union { float f; uint32_t u; } v; v.f = f;
  uint32_t u = v.u;
  uint32_t r = (u + 0x7FFFu + ((u >> 16) & 1u)) >> 16;
  return (unsigned short)r;
}
__device__ __forceinline__ float bf2f(uint32_t bits16) {
  union { uint32_t u; float f; } v; v.u = bits16 << 16; return v.f;
}
__device__ __forceinline__ unsigned short cvt_bf16(float f) {
  __bf16 b = (__bf16)f;
  return __builtin_bit_cast(unsigned short, b);
}
__device__ __forceinline__ void gld16(const void* g, void* l) {
  __builtin_amdgcn_global_load_lds(
      (const __attribute__((address_space(1))) void*)g,
      (__attribute__((address_space(3))) void*)l, 16, 0, 0);
}
__device__ __forceinline__ bf16x8 cvt8(const float4& f0, const float4& f1) {
  f32x8 fv;
  fv[0]=f0.x; fv[1]=f0.y; fv[2]=f0.z; fv[3]=f0.w;
  fv[4]=f1.x; fv[5]=f1.y; fv[6]=f1.z; fv[7]=f1.w;
  return __builtin_convertvector(fv, bf16x8);
}

// ---------------- K0: convert weights f32 -> bf16 + zero ws region ----------------
__global__ void convert_weights(const float* __restrict__ W1,
                                const float* __restrict__ W2a,
                                const float* __restrict__ W2b,
                                unsigned short* __restrict__ W1b,
                                unsigned short* __restrict__ W2ab,
                                unsigned short* __restrict__ W2bb,
                                float* __restrict__ zws) {
  int i = blockIdx.x * 256 + threadIdx.x;
  if (i < 512 * 1024) W1b[i] = f2bf(W1[i]);
  if (i < 256 * 512) { W2ab[i] = f2bf(W2a[i]); W2bb[i] = f2bf(W2b[i]); }
  if (i < ZERO_F32) zws[i] = 0.f;   // mug, lvg, (legacy)
}

// ---------------- K1: x = relu(h @ W1^T + b1) -> bf16 ----------------
// (R16/R18-exact, measured best) 256x256 tile, BK=32, 512 threads = 8 waves
// (2M x 4N), per-wave 128x64 (acc[8][4]). P0: frag reads + A ds_write(t+1)
// + A-loads(t+2); P1: frag reads + B-gld16(t+2). Counted vmcnt(6) boundary;
// swizzled LDS (0 conflicts); bijective XCD remap.
__global__ __launch_bounds__(512, 2) void gemm1(
    const float* __restrict__ h, const unsigned short* __restrict__ W1b,
    const float* __restrict__ b1, unsigned short* __restrict__ xb) {
  __shared__ __align__(16) unsigned short lds[40960];  // 80 KB
  unsigned short* const A0 = lds;
  unsigned short* const A1 = lds + 8192;
  unsigned short* const B0 = lds + 16384;
  unsigned short* const B1 = lds + 24576;
  unsigned short* const B2 = lds + 32768;

  const int t  = threadIdx.x;
  const int l  = t & 63;
  const int w  = t >> 6;
  const int wm = w >> 2;
  const int wn = w & 3;
  const int g  = l >> 4;
  const int lr = l & 15;

  const int i   = blockIdx.x;
  const int xcd = i & 7;
  const int pos = i >> 3;
  const int v   = xcd * 49 + pos;
  const int rt  = v >> 1;
  const int ct  = v & 1;
  const int rowBase = rt * 256;
  const int colBase = ct * 256;

  const int tr = t >> 1;
  const int hh = t & 1;
  int gr = rowBase + tr; if (gr >= NPATCH) gr = NPATCH - 1;
  const float* ah = h + (size_t)gr * 1024 + hh * 16;
  const int sw  = (tr >> 1) & 3;
  const int aw0 = tr * 32 + ((hh * 2)     ^ sw) * 8;
  const int aw1 = tr * 32 + ((hh * 2 + 1) ^ sw) * 8;

  const int bj = (t & 3) ^ ((t >> 3) & 3);
  const unsigned short* bh  = W1b + (size_t)(colBase + (t >> 2)) * 1024 + bj * 8;
  const unsigned short* bh2 = bh + (size_t)128 * 1024;
  const int bd0 = t * 8;
  const int bd1 = 4096 + t * 8;

  const int rs = (g ^ ((lr >> 1) & 3)) * 8;
  const int abase = (wm * 128 + lr) * 32 + rs;
  const int bbase = (wn * 64 + lr) * 32 + rs;

  f32x4 acc[8][4];
#pragma unroll
  for (int m = 0; m < 8; ++m)
#pragma unroll
    for (int n = 0; n < 4; ++n) acc[m][n] = (f32x4){0.f, 0.f, 0.f, 0.f};

  unsigned short *pAr = A0, *pAw = A1;
  unsigned short *pBr = B0, *pBr1 = B1, *pBw = B2;

  float4 q0, q1, q2, q3;
  {
    gld16(bh, pBr + bd0); gld16(bh2, pBr + bd1);
    float4 f0 = *(const float4*)(ah + 0);
    float4 f1 = *(const float4*)(ah + 4);
    float4 f2 = *(const float4*)(ah + 8);
    float4 f3 = *(const float4*)(ah + 12);
    *(bf16x8*)(pAr + aw0) = cvt8(f0, f1);
    *(bf16x8*)(pAr + aw1) = cvt8(f2, f3);
    q0 = *(const float4*)(ah + 32);
    q1 = *(const float4*)(ah + 36);
    q2 = *(const float4*)(ah + 40);
    q3 = *(const float4*)(ah + 44);
    gld16(bh + 32, pBr1 + bd0); gld16(bh2 + 32, pBr1 + bd1);
  }
  asm volatile("s_waitcnt lgkmcnt(0)\n\ts_barrier" ::: "memory");

  for (int kt = 0; kt < 32; ++kt) {
    const int ka = ((kt + 2 <= 31) ? (kt + 2) : 31) * 32;
    bf16x8 af[4], bf[4];
#pragma unroll
    for (int m = 0; m < 4; ++m)
      af[m] = *(const bf16x8*)(pAr + abase + m * 512);
#pragma unroll
    for (int n = 0; n < 4; ++n)
      bf[n] = *(const bf16x8*)(pBr + bbase + n * 512);
    *(bf16x8*)(pAw + aw0) = cvt8(q0, q1);
    *(bf16x8*)(pAw + aw1) = cvt8(q2, q3);
    q0 = *(const float4*)(ah + ka + 0);
    q1 = *(const float4*)(ah + ka + 4);
    q2 = *(const float4*)(ah + ka + 8);
    q3 = *(const float4*)(ah + ka + 12);
    __builtin_amdgcn_sched_barrier(0);
    __builtin_amdgcn_s_barrier();
    __builtin_amdgcn_s_setprio(1);
#pragma unroll
    for (int m = 0; m < 4; ++m)
#pragma unroll
      for (int n = 0; n < 4; ++n)
        acc[m][n] = __builtin_amdgcn_mfma_f32_16x16x32_bf16(af[m], bf[n], acc[m][n], 0, 0, 0);
    __builtin_amdgcn_s_setprio(0);
    __builtin_amdgcn_s_barrier();
#pragma unroll
    for (int m = 0; m < 4; ++m)
      af[m] = *(const bf16x8*)(pAr + abase + (m + 4) * 512);
    gld16(bh + ka, pBw + bd0);
    gld16(bh2 + ka, pBw + bd1);
    __builtin_amdgcn_sched_barrier(0);
    __builtin_amdgcn_s_barrier();
    __builtin_amdgcn_s_setprio(1);
#pragma unroll
    for (int m = 0; m < 4; ++m)
#pragma unroll
      for (int n = 0; n < 4; ++n)
        acc[m + 4][n] = __builtin_amdgcn_mfma_f32_16x16x32_bf16(af[m], bf[n], acc[m + 4][n], 0, 0, 0);
    __builtin_amdgcn_s_setprio(0);
    asm volatile("s_waitcnt vmcnt(6) lgkmcnt(0)\n\ts_barrier" ::: "memory");
    unsigned short* tA = pAr; pAr = pAw; pAw = tA;
    unsigned short* tB = pBr; pBr = pBr1; pBr1 = pBw; pBw = tB;
  }
  asm volatile("s_waitcnt vmcnt(0) lgkmcnt(0)" ::: "memory");

  float b1v[4];
#pragma unroll
  for (int n = 0; n < 4; ++n) b1v[n] = b1[colBase + wn * 64 + n * 16 + lr];
#pragma unroll
  for (int m = 0; m < 8; ++m) {
    const int rb0 = rowBase + wm * 128 + m * 16 + g * 4;
#pragma unroll
    for (int r = 0; r < 4; ++r) {
      const int row = rb0 + r;
      if (row < NPATCH) {
        unsigned short* xrow = xb + (size_t)row * 512 + colBase + wn * 64;
#pragma unroll
        for (int n = 0; n < 4; ++n) {
          float vv = acc[m][n][r] + b1v[n];
          vv = vv > 0.f ? vv : 0.f;
          xrow[n * 16 + lr] = cvt_bf16(vv);
        }
      }
    }
  }
}

// ---------------- K2: fa=sig(x@W2a^T+b2a), fb=tanh(x@W2b^T+b2b),
//                      params=(fa*fb)@W3^T+b3, scatter mu/logvar ----------------
// (R14 version) 128x256 tile, 8 waves, all operands via gld16, swizzled
// frag reads, dbuf + one __syncthreads/K-step.
__global__ __launch_bounds__(512) void gemm2(
    const unsigned short* __restrict__ xb,
    const unsigned short* __restrict__ W2ab, const unsigned short* __restrict__ W2bb,
    const float* __restrict__ b2a, const float* __restrict__ b2b,
    const float* __restrict__ W3, const float* __restrict__ b3,
    const int* __restrict__ coords,
    float* __restrict__ mug, float* __restrict__ lvg) {
  __shared__ __align__(16) unsigned short xs[2][128 * 32];   // 16 KB
  __shared__ __align__(16) unsigned short was[2][256 * 32];  // 32 KB
  __shared__ __align__(16) unsigned short wbs[2][256 * 32];  // 32 KB
  __shared__ float pmu_s[4][128];
  __shared__ float plv_s[4][128];

  const int t  = threadIdx.x;
  const int l  = t & 63;
  const int w  = t >> 6;        // 0..7
  const int wm = w >> 2;        // 0..1 (row half: 64 rows)
  const int wn = w & 3;         // 0..3 (col quarter: 64 cols)
  const int g  = l >> 4;
  const int lr = l & 15;
  const int rowBase = blockIdx.x * 128;

  const int bj = (t & 3) ^ ((t >> 3) & 3);
  const unsigned short* xsrc   = xb   + (size_t)(rowBase + (t >> 2)) * 512 + bj * 8;
  const unsigned short* wasrc0 = W2ab + (size_t)(t >> 2) * 512 + bj * 8;
  const unsigned short* wasrc1 = wasrc0 + (size_t)128 * 512;
  const unsigned short* wbsrc0 = W2bb + (size_t)(t >> 2) * 512 + bj * 8;
  const unsigned short* wbsrc1 = wbsrc0 + (size_t)128 * 512;
  const int d0 = t * 8;
  const int d1 = 4096 + t * 8;

  const int rslot = (g ^ ((lr >> 1) & 3)) * 8;

  f32x4 aa[4][4], ab[4][4];
#pragma unroll
  for (int m = 0; m < 4; ++m)
#pragma unroll
    for (int n = 0; n < 4; ++n) {
      aa[m][n] = (f32x4){0.f, 0.f, 0.f, 0.f};
      ab[m][n] = (f32x4){0.f, 0.f, 0.f, 0.f};
    }

  {
    gld16(xsrc,   &xs[0][d0]);
    gld16(wasrc0, &was[0][d0]);
    gld16(wasrc1, &was[0][d1]);
    gld16(wbsrc0, &wbs[0][d0]);
    gld16(wbsrc1, &wbs[0][d1]);
  }
  __syncthreads();

  int cur = 0;
  for (int kt = 0; kt < 16; ++kt) {
    if (kt < 15) {
      const int k0 = (kt + 1) * 32;
      gld16(xsrc + k0,   &xs[cur ^ 1][d0]);
      gld16(wasrc0 + k0, &was[cur ^ 1][d0]);
      gld16(wasrc1 + k0, &was[cur ^ 1][d1]);
      gld16(wbsrc0 + k0, &wbs[cur ^ 1][d0]);
      gld16(wbsrc1 + k0, &wbs[cur ^ 1][d1]);
    }
    bf16x8 af[4], ba[4], bb[4];
#pragma unroll
    for (int m = 0; m < 4; ++m)
      af[m] = *(const bf16x8*)&xs[cur][(wm * 64 + m * 16 + lr) * 32 + rslot];
#pragma unroll
    for (int n = 0; n < 4; ++n) {
      const int brow = (wn * 64 + n * 16 + lr) * 32 + rslot;
      ba[n] = *(const bf16x8*)&was[cur][brow];
      bb[n] = *(const bf16x8*)&wbs[cur][brow];
    }
#pragma unroll
    for (int m = 0; m < 4; ++m)
#pragma unroll
      for (int n = 0; n < 4; ++n) {
        aa[m][n] = __builtin_amdgcn_mfma_f32_16x16x32_bf16(af[m], ba[n], aa[m][n], 0, 0, 0);
        ab[m][n] = __builtin_amdgcn_mfma_f32_16x16x32_bf16(af[m], bb[n], ab[m][n], 0, 0, 0);
      }
    __syncthreads();
    cur ^= 1;
  }

  float b2av[4], b2bv[4], w30v[4], w31v[4];
#pragma unroll
  for (int n = 0; n < 4; ++n) {
    const int col = wn * 64 + n * 16 + lr;
    b2av[n] = b2a[col]; b2bv[n] = b2b[col];
    w30v[n] = W3[col];  w31v[n] = W3[256 + col];
  }
#pragma unroll
  for (int m = 0; m < 4; ++m) {
#pragma unroll
    for (int r = 0; r < 4; ++r) {
      float pm = 0.f, pl = 0.f;
#pragma unroll
      for (int n = 0; n < 4; ++n) {
        float a = 1.f / (1.f + __expf(-(aa[m][n][r] + b2av[n])));
        float b = tanhf(ab[m][n][r] + b2bv[n]);
        float p = a * b;
        pm += p * w30v[n];
        pl += p * w31v[n];
      }
#pragma unroll
      for (int d = 1; d < 16; d <<= 1) {
        pm += __shfl_xor(pm, d, 64);
        pl += __shfl_xor(pl, d, 64);
      }
      if (lr == 0) {
        pmu_s[wn][wm * 64 + m * 16 + g * 4 + r] = pm;
        plv_s[wn][wm * 64 + m * 16 + g * 4 + r] = pl;
      }
    }
  }
  __syncthreads();
  if (t < 128) {
    float mu = pmu_s[0][t] + pmu_s[1][t] + pmu_s[2][t] + pmu_s[3][t] + b3[0];
    float lv = plv_s[0][t] + plv_s[1][t] + plv_s[2][t] + plv_s[3][t] + b3[1];
    int row = rowBase + t;
    if (row < NPATCH) {
      int gx = coords[2 * row] >> 8;
      int gy = coords[2 * row + 1] >> 8;
      int cell = gy * GC + gx;
      mug[cell] = mu;
      lvg[cell] = lv;
    }
  }
}

// ---------------- K3: kl_div (all cells) + gather-with-inline-conv +
//                      per-block partial sums (fused grid_ops+patch_pass) ----------------
// 392 blocks x 256 threads. Blocks 0..255 also write kl_div for their 256
// cells. Each row's attention a = sigmoid(conv3x3(mug)[cell] +
// eps[cell]*exp(lv/2)) computed INLINE from mug/lvg (L2-resident) -- the Ag
// array round-trip and the separate grid_ops kernel are eliminated.
__global__ __launch_bounds__(256) void patch_pass(
    const float* __restrict__ mug, const float* __restrict__ lvg,
    const float* __restrict__ eps, const float* __restrict__ kern,
    const int* __restrict__ slide, const int* __restrict__ coords,
    const unsigned short* __restrict__ xb, float* __restrict__ out_kl,
    float* __restrict__ out_pA, float* __restrict__ Mpart2,
    float* __restrict__ sumAp) {
  __shared__ float als[128];
  __shared__ float sred[2];
  const int t = threadIdx.x;
  const int base = blockIdx.x * 128;

  // grid_ops part: kl_div for all 65536 cells (blocks 0..255)
  if (blockIdx.x < 256) {
    const int cell = blockIdx.x * 256 + t;
    const float mu = mug[cell], lv = lvg[cell];
    const int sl = slide[0];
    const float pm  = (sl == 0) ? -5.0f : 0.0f;
    const float plv = (sl == 0) ? -1.0f : 3.0f;
    const float d = pm - mu;
    out_kl[cell] = (plv - lv) * 0.5f + (lv * lv + d * d) / (2.0f * plv * plv) - 0.5f;
  }

  // gather part: a = sigmoid(conv3x3(mug)[cell] + eps[cell]*exp(lv/2))
  if (t < 128) {
    const int row = base + t;
    float a = 0.f;
    if (row < NPATCH) {
      const int gx = coords[2 * row] >> 8;
      const int gy = coords[2 * row + 1] >> 8;
      const int cell = gy * GC + gx;
      float s = 0.f;
#pragma unroll
      for (int dy = 0; dy < 3; ++dy) {
#pragma unroll
        for (int dx = 0; dx < 3; ++dx) {
          const int y = gy + dy - 1, x = gx + dx - 1;
          if (y >= 0 && y < GC && x >= 0 && x < GC)
            s += mug[y * GC + x] * kern[dy * 3 + dx];
        }
      }
      const float sample = s + eps[cell] * __expf(0.5f * lvg[cell]);
      a = 1.f / (1.f + __expf(-sample));
      out_pA[row] = a;
    }
    als[t] = a;
    float sa = a;
#pragma unroll
    for (int d = 1; d < 64; d <<= 1) sa += __shfl_xor(sa, d, 64);
    if ((t & 63) == 0) sred[t >> 6] = sa;
  }
  __syncthreads();
  if (t == 0) sumAp[blockIdx.x] = sred[0] + sred[1];

  int nrows = NPATCH - base;
  if (nrows > 128) nrows = 128;
  if (nrows < 0) nrows = 0;
  float m0 = 0.f, m1 = 0.f;
  for (int r = 0; r < nrows; ++r) {
    const float av = als[r];
    const uint32_t v = *(const uint32_t*)(xb + (size_t)(base + r) * 512 + t * 2);
    m0 += av * bf2f(v & 0xFFFFu);
    m1 += av * bf2f(v >> 16);
  }
  Mpart2[(size_t)blockIdx.x * 512 + 2 * t]     = m0;
  Mpart2[(size_t)blockIdx.x * 512 + 2 * t + 1] = m1;
}

// ---------------- K4: cross-block reduce + logits, softmax, argmax ----------------
__global__ __launch_bounds__(256) void finalize(
    const float* __restrict__ Mpart2, const float* __restrict__ sumAp,
    const float* __restrict__ Wc, const float* __restrict__ bc,
    float* __restrict__ out) {
  __shared__ float red0[4], red1[4], reds[4];
  const int t = threadIdx.x;  // 256 threads; thread owns cols 2t, 2t+1
  const int c0 = 2 * t, c1 = 2 * t + 1;
  float m0 = 0.f, m1 = 0.f;
  for (int b = 0; b < 392; ++b) {
    m0 += Mpart2[(size_t)b * 512 + c0];
    m1 += Mpart2[(size_t)b * 512 + c1];
  }
  float sa = 0.f;
  if (t < 196) sa = sumAp[t] + ((t + 196 < 392) ? sumAp[t + 196] : 0.f);
#pragma unroll
  for (int d = 1; d < 64; d <<= 1) sa += __shfl_xor(sa, d, 64);
  if ((t & 63) == 0) reds[t >> 6] = sa;

  float l0 = m0 * Wc[c0] + m1 * Wc[c1];
  float l1 = m0 * Wc[512 + c0] + m1 * Wc[512 + c1];
#pragma unroll
  for (int d = 1; d < 64; d <<= 1) {
    l0 += __shfl_xor(l0, d, 64);
    l1 += __shfl_xor(l1, d, 64);
  }
  if ((t & 63) == 0) { red0[t >> 6] = l0; red1[t >> 6] = l1; }
  __syncthreads();
  if (t == 0) {
    const float s = reds[0] + reds[1] + reds[2] + reds[3];
    l0 = (red0[0] + red0[1] + red0[2] + red0[3]) / s + bc[0];
    l1 = (red1[0] + red1[1] + red1[2] + red1[3]) / s + bc[1];
    float mx = fmaxf(l0, l1);
    float e0 = __expf(l0 - mx), e1 = __expf(l1 - mx);
    float inv = 1.f / (e0 + e1);
    float p0 = e0 * inv, p1 = e1 * inv;
    out[0] = l0; out[1] = l1;            // top_instance
    out[2] = p0; out[3] = p1;            // Y_prob
    out[4] = (l1 > l0) ? 1.0f : 0.0f;    // Y_hat
    out[65541] = p0; out[65542] = p1;    // y_probs
  }
}

extern "C" void kernel_launch(void* const* d_in, const int* in_sizes, int n_in,
                              void* d_out, int out_size, void* d_ws, size_t ws_size,
                              hipStream_t stream) {
  const float* h      = (const float*)d_in[0];
  const int*   coords = (const int*)d_in[1];
  const float* eps    = (const float*)d_in[2];
  const float* W1     = (const float*)d_in[3];
  const float* b1     = (const float*)d_in[4];
  const float* W2a    = (const float*)d_in[5];
  const float* b2a    = (const float*)d_in[6];
  const float* W2b    = (const float*)d_in[7];
  const float* b2b    = (const float*)d_in[8];
  const float* W3     = (const float*)d_in[9];
  const float* b3     = (const float*)d_in[10];
  const float* Wc     = (const float*)d_in[11];
  const float* bc     = (const float*)d_in[12];
  const float* kern   = (const float*)d_in[13];
  const int*   slide  = (const int*)d_in[16];
  float* out = (float*)d_out;
  char*  ws  = (char*)d_ws;

  unsigned short* xb   = (unsigned short*)(ws + XB_OFF);
  unsigned short* W1b  = (unsigned short*)(ws + W1B_OFF);
  unsigned short* W2ab = (unsigned short*)(ws + W2AB_OFF);
  unsigned short* W2bb = (unsigned short*)(ws + W2BB_OFF);
  float* mug    = (float*)(ws + MUG_OFF);
  float* lvg    = (float*)(ws + LVG_OFF);
  float* Mpart2 = (float*)(ws + MPART2_OFF);
  float* sumAp  = (float*)(ws + SUMAP_OFF);

  convert_weights<<<2048, 256, 0, stream>>>(W1, W2a, W2b, W1b, W2ab, W2bb,
                                            (float*)(ws + MUG_OFF));
  gemm1<<<392, 512, 0, stream>>>(h, W1b, b1, xb);
  gemm2<<<391, 512, 0, stream>>>(xb, W2ab, W2bb, b2a, b2b, W3, b3, coords, mug, lvg);
  patch_pass<<<392, 256, 0, stream>>>(mug, lvg, eps, kern, slide, coords, xb,
                                      out + 5, out + 65543, Mpart2, sumAp);
  finalize<<<1, 256, 0, stream>>>(Mpart2, sumAp, Wc, bc, out);
}

// Round 21
// 181.464 us; speedup vs baseline: 1.0105x; 1.0087x over previous
//
#include <hip/hip_runtime.h>
#include <hip/hip_bf16.h>
#include <cstdint>
#include <cstddef>

#define NPATCH 50000
#define GC 256

typedef __bf16 bf16x8 __attribute__((ext_vector_type(8)));
typedef float  f32x4  __attribute__((ext_vector_type(4)));
typedef float  f32x8  __attribute__((ext_vector_type(8)));

// ---------------- workspace layout (bytes) ----------------
static constexpr size_t XB_OFF    = 0;                         // bf16 x [50048][512]
static constexpr size_t XB_BYTES  = (size_t)50048 * 512 * 2;
static constexpr size_t W1B_OFF   = XB_OFF + XB_BYTES;         // bf16 W1 [512][1024]
static constexpr size_t W1B_BYTES = (size_t)512 * 1024 * 2;
static constexpr size_t W2AB_OFF  = W1B_OFF + W1B_BYTES;       // bf16 W2a [256][512]
static constexpr size_t W2X_BYTES = (size_t)256 * 512 * 2;
static constexpr size_t W2BB_OFF  = W2AB_OFF + W2X_BYTES;      // bf16 W2b [256][512]
static constexpr size_t MUG_OFF   = W2BB_OFF + W2X_BYTES;      // f32 [65536]
static constexpr size_t LVG_OFF   = MUG_OFF + (size_t)65536 * 4;
static constexpr size_t AG_OFF    = LVG_OFF + (size_t)65536 * 4;  // (legacy, unused)
static constexpr size_t MPART_OFF = AG_OFF + (size_t)65536 * 4;   // (legacy, unused)
static constexpr size_t SUMA_OFF  = MPART_OFF + (size_t)512 * 4;
static constexpr size_t ZERO_BYTES = SUMA_OFF + 4 - MUG_OFF;   // zero mug..sumA
static constexpr int    ZERO_F32   = (int)(ZERO_BYTES / 4);    // 197121 floats
static constexpr size_t MPART2_OFF = ((SUMA_OFF + 4 + 63) / 64) * 64; // f32 [392][512]
static constexpr size_t SUMAP_OFF  = MPART2_OFF + (size_t)392 * 512 * 4; // f32 [392]

__device__ __forceinline__ unsigned short f2bf(float f) {
  union { float f; uint32_t u; } v; v.f = f;
  uint32_t u = v.u;
  uint32_t r = (u + 0x7FFFu + ((u >> 16) & 1u)) >> 16;
  return (unsigned short)r;
}
__device__ __forceinline__ float bf2f(uint32_t bits16) {
  union { uint32_t u; float f; } v; v.u = bits16 << 16; return v.f;
}
__device__ __forceinline__ unsigned short cvt_bf16(float f) {
  __bf16 b = (__bf16)f;
  return __builtin_bit_cast(unsigned short, b);
}
__device__ __forceinline__ void gld16(const void* g, void* l) {
  __builtin_amdgcn_global_load_lds(
      (const __attribute__((address_space(1))) void*)g,
      (__attribute__((address_space(3))) void*)l, 16, 0, 0);
}
__device__ __forceinline__ bf16x8 cvt8(const float4& f0, const float4& f1) {
  f32x8 fv;
  fv[0]=f0.x; fv[1]=f0.y; fv[2]=f0.z; fv[3]=f0.w;
  fv[4]=f1.x; fv[5]=f1.y; fv[6]=f1.z; fv[7]=f1.w;
  return __builtin_convertvector(fv, bf16x8);
}

// ---------------- K0: convert weights f32 -> bf16 + zero ws region ----------------
__global__ void convert_weights(const float* __restrict__ W1,
                                const float* __restrict__ W2a,
                                const float* __restrict__ W2b,
                                unsigned short* __restrict__ W1b,
                                unsigned short* __restrict__ W2ab,
                                unsigned short* __restrict__ W2bb,
                                float* __restrict__ zws) {
  int i = blockIdx.x * 256 + threadIdx.x;
  if (i < 512 * 1024) W1b[i] = f2bf(W1[i]);
  if (i < 256 * 512) { W2ab[i] = f2bf(W2a[i]); W2bb[i] = f2bf(W2b[i]); }
  if (i < ZERO_F32) zws[i] = 0.f;
}

// ---------------- K1: x = relu(h @ W1^T + b1) -> bf16 ----------------
// R16 schedule at HALF block size for 2-block/CU co-residency (latency
// overlap, m114): 128x256 tile, BK=32, 256 threads = 4 waves (2M x 2N),
// per-wave 64x128 (acc[4][8], 232 regs -> 2 waves/SIMD -> 2 blocks/CU;
// LDS 64KB -> 128KB/CU). Phases: P0 {af m0-3 + bf n0-3 + A ds_write(t+1) +
// A-loads(t+2); 16 MFMA}; P1 {bf n4-7 + B gld16(t+2) x4; 16 MFMA}.
// Ledger: ds_write waits vmcnt(4) = A(t+1), leaves B(t+1)x4 in flight;
// boundary vmcnt(8) retires exactly B(t)x4 (full-tile cover). Swizzled LDS
// (0 conflicts); bijective XCD remap over 782 = 8*97+6 (m204).
__global__ __launch_bounds__(256, 2) void gemm1(
    const float* __restrict__ h, const unsigned short* __restrict__ W1b,
    const float* __restrict__ b1, unsigned short* __restrict__ xb) {
  __shared__ __align__(16) unsigned short lds[32768];  // 64 KB
  unsigned short* const A0 = lds;            // 2 x 8 KB A bufs (4096 ushorts)
  unsigned short* const A1 = lds + 4096;
  unsigned short* const B0 = lds + 8192;     // 3 x 16 KB B bufs (8192 ushorts)
  unsigned short* const B1 = lds + 16384;
  unsigned short* const B2 = lds + 24576;

  const int t  = threadIdx.x;
  const int l  = t & 63;
  const int w  = t >> 6;          // 0..3
  const int wm = w >> 1;          // 0..1 (64-row half)
  const int wn = w & 1;           // 0..1 (128-col half)
  const int g  = l >> 4;
  const int lr = l & 15;

  // bijective XCD remap (m204): 782 = 6*98 + 2*97
  const int i   = blockIdx.x;
  const int xcd = i & 7;
  const int pos = i >> 3;
  const int v   = (xcd < 6 ? xcd * 98 : 6 * 98 + (xcd - 6) * 97) + pos;
  const int rt  = v >> 1;          // 0..390
  const int ct  = v & 1;
  const int rowBase = rt * 128;
  const int colBase = ct * 256;

  // ---- A staging: thread t -> row t>>1 (0..127), half hh = t&1 ----
  const int tr = t >> 1;
  const int hh = t & 1;
  int gr = rowBase + tr; if (gr >= NPATCH) gr = NPATCH - 1;
  const float* ah = h + (size_t)gr * 1024 + hh * 16;
  const int sw  = (tr >> 1) & 3;
  const int aw0 = tr * 32 + ((hh * 2)     ^ sw) * 8;
  const int aw1 = tr * 32 + ((hh * 2 + 1) ^ sw) * 8;

  // ---- B staging: 4 gld16/thread; col group (t>>2)+64r, chunk inv-swizzled
  const int bj = (t & 3) ^ ((t >> 3) & 3);
  const unsigned short* bh  = W1b + (size_t)(colBase + (t >> 2)) * 1024 + bj * 8;
  const unsigned short* bh2 = bh + (size_t)64 * 1024;
  const unsigned short* bh3 = bh + (size_t)128 * 1024;
  const unsigned short* bh4 = bh + (size_t)192 * 1024;
  const int bd = t * 8;            // + r*2048 per col group

  const int rs = (g ^ ((lr >> 1) & 3)) * 8;
  const int abase = (wm * 64 + lr) * 32 + rs;    // + m*512
  const int bbase = (wn * 128 + lr) * 32 + rs;   // + n*512

  f32x4 acc[4][8];
#pragma unroll
  for (int m = 0; m < 4; ++m)
#pragma unroll
    for (int n = 0; n < 8; ++n) acc[m][n] = (f32x4){0.f, 0.f, 0.f, 0.f};

  unsigned short *pAr = A0, *pAw = A1;
  unsigned short *pBr = B0, *pBr1 = B1, *pBw = B2;

  float4 q0, q1, q2, q3;
  {
    gld16(bh,  pBr + bd);        gld16(bh2, pBr + 2048 + bd);   // B(0)
    gld16(bh3, pBr + 4096 + bd); gld16(bh4, pBr + 6144 + bd);
    float4 f0 = *(const float4*)(ah + 0);
    float4 f1 = *(const float4*)(ah + 4);
    float4 f2 = *(const float4*)(ah + 8);
    float4 f3 = *(const float4*)(ah + 12);
    *(bf16x8*)(pAr + aw0) = cvt8(f0, f1);    // A(0) (drains B(0) too)
    *(bf16x8*)(pAr + aw1) = cvt8(f2, f3);
    q0 = *(const float4*)(ah + 32);          // A(1)
    q1 = *(const float4*)(ah + 36);
    q2 = *(const float4*)(ah + 40);
    q3 = *(const float4*)(ah + 44);
    gld16(bh + 32,  pBr1 + bd);        gld16(bh2 + 32, pBr1 + 2048 + bd);  // B(1)
    gld16(bh3 + 32, pBr1 + 4096 + bd); gld16(bh4 + 32, pBr1 + 6144 + bd);
  }
  asm volatile("s_waitcnt lgkmcnt(0)\n\ts_barrier" ::: "memory");
  // entering loop: outstanding = A(1)x4, B(1)x4

  for (int kt = 0; kt < 32; ++kt) {
    const int ka = ((kt + 2 <= 31) ? (kt + 2) : 31) * 32;
    // ---- P0: af m0-3 + bf n0-3 + A ds_write(t+1) + A-loads(t+2) ----
    bf16x8 af[4], bf[4];
#pragma unroll
    for (int m = 0; m < 4; ++m)
      af[m] = *(const bf16x8*)(pAr + abase + m * 512);
#pragma unroll
    for (int n = 0; n < 4; ++n)
      bf[n] = *(const bf16x8*)(pBr + bbase + n * 512);
    *(bf16x8*)(pAw + aw0) = cvt8(q0, q1);   // compiler: vmcnt(4) -> A(t+1)
    *(bf16x8*)(pAw + aw1) = cvt8(q2, q3);
    q0 = *(const float4*)(ah + ka + 0);     // issue A(t+2)
    q1 = *(const float4*)(ah + ka + 4);
    q2 = *(const float4*)(ah + ka + 8);
    q3 = *(const float4*)(ah + ka + 12);
    __builtin_amdgcn_sched_barrier(0);
    __builtin_amdgcn_s_barrier();
    __builtin_amdgcn_s_setprio(1);
#pragma unroll
    for (int m = 0; m < 4; ++m)
#pragma unroll
      for (int n = 0; n < 4; ++n)
        acc[m][n] = __builtin_amdgcn_mfma_f32_16x16x32_bf16(af[m], bf[n], acc[m][n], 0, 0, 0);
    __builtin_amdgcn_s_setprio(0);
    __builtin_amdgcn_s_barrier();
    // ---- P1: bf n4-7 + B gld16(t+2) x4 ----
#pragma unroll
    for (int n = 0; n < 4; ++n)
      bf[n] = *(const bf16x8*)(pBr + bbase + (n + 4) * 512);
    gld16(bh + ka,  pBw + bd);        gld16(bh2 + ka, pBw + 2048 + bd);
    gld16(bh3 + ka, pBw + 4096 + bd); gld16(bh4 + ka, pBw + 6144 + bd);
    __builtin_amdgcn_sched_barrier(0);
    __builtin_amdgcn_s_barrier();
    __builtin_amdgcn_s_setprio(1);
#pragma unroll
    for (int m = 0; m < 4; ++m)
#pragma unroll
      for (int n = 0; n < 4; ++n)
        acc[m][n + 4] = __builtin_amdgcn_mfma_f32_16x16x32_bf16(af[m], bf[n], acc[m][n + 4], 0, 0, 0);
    __builtin_amdgcn_s_setprio(0);
    // boundary: retire B(t)x4; A(t+2)x4 + B(t+2)x4 = 8 stay in flight
    asm volatile("s_waitcnt vmcnt(8) lgkmcnt(0)\n\ts_barrier" ::: "memory");
    unsigned short* tA = pAr; pAr = pAw; pAw = tA;
    unsigned short* tB = pBr; pBr = pBr1; pBr1 = pBw; pBw = tB;
  }
  asm volatile("s_waitcnt vmcnt(0) lgkmcnt(0)" ::: "memory");

  float b1v[8];
#pragma unroll
  for (int n = 0; n < 8; ++n) b1v[n] = b1[colBase + wn * 128 + n * 16 + lr];
#pragma unroll
  for (int m = 0; m < 4; ++m) {
    const int rb0 = rowBase + wm * 64 + m * 16 + g * 4;
#pragma unroll
    for (int r = 0; r < 4; ++r) {
      const int row = rb0 + r;
      if (row < NPATCH) {
        unsigned short* xrow = xb + (size_t)row * 512 + colBase + wn * 128;
#pragma unroll
        for (int n = 0; n < 8; ++n) {
          float vv = acc[m][n][r] + b1v[n];
          vv = vv > 0.f ? vv : 0.f;
          xrow[n * 16 + lr] = cvt_bf16(vv);
        }
      }
    }
  }
}

// ---------------- K2: fa=sig(x@W2a^T+b2a), fb=tanh(x@W2b^T+b2b),
//                      params=(fa*fb)@W3^T+b3, scatter mu/logvar ----------------
// (R14 version) 128x256 tile, 8 waves, all operands via gld16, swizzled
// frag reads, dbuf + one __syncthreads/K-step.
__global__ __launch_bounds__(512) void gemm2(
    const unsigned short* __restrict__ xb,
    const unsigned short* __restrict__ W2ab, const unsigned short* __restrict__ W2bb,
    const float* __restrict__ b2a, const float* __restrict__ b2b,
    const float* __restrict__ W3, const float* __restrict__ b3,
    const int* __restrict__ coords,
    float* __restrict__ mug, float* __restrict__ lvg) {
  __shared__ __align__(16) unsigned short xs[2][128 * 32];   // 16 KB
  __shared__ __align__(16) unsigned short was[2][256 * 32];  // 32 KB
  __shared__ __align__(16) unsigned short wbs[2][256 * 32];  // 32 KB
  __shared__ float pmu_s[4][128];
  __shared__ float plv_s[4][128];

  const int t  = threadIdx.x;
  const int l  = t & 63;
  const int w  = t >> 6;        // 0..7
  const int wm = w >> 2;        // 0..1 (row half: 64 rows)
  const int wn = w & 3;         // 0..3 (col quarter: 64 cols)
  const int g  = l >> 4;
  const int lr = l & 15;
  const int rowBase = blockIdx.x * 128;

  const int bj = (t & 3) ^ ((t >> 3) & 3);
  const unsigned short* xsrc   = xb   + (size_t)(rowBase + (t >> 2)) * 512 + bj * 8;
  const unsigned short* wasrc0 = W2ab + (size_t)(t >> 2) * 512 + bj * 8;
  const unsigned short* wasrc1 = wasrc0 + (size_t)128 * 512;
  const unsigned short* wbsrc0 = W2bb + (size_t)(t >> 2) * 512 + bj * 8;
  const unsigned short* wbsrc1 = wbsrc0 + (size_t)128 * 512;
  const int d0 = t * 8;
  const int d1 = 4096 + t * 8;

  const int rslot = (g ^ ((lr >> 1) & 3)) * 8;

  f32x4 aa[4][4], ab[4][4];
#pragma unroll
  for (int m = 0; m < 4; ++m)
#pragma unroll
    for (int n = 0; n < 4; ++n) {
      aa[m][n] = (f32x4){0.f, 0.f, 0.f, 0.f};
      ab[m][n] = (f32x4){0.f, 0.f, 0.f, 0.f};
    }

  {
    gld16(xsrc,   &xs[0][d0]);
    gld16(wasrc0, &was[0][d0]);
    gld16(wasrc1, &was[0][d1]);
    gld16(wbsrc0, &wbs[0][d0]);
    gld16(wbsrc1, &wbs[0][d1]);
  }
  __syncthreads();

  int cur = 0;
  for (int kt = 0; kt < 16; ++kt) {
    if (kt < 15) {
      const int k0 = (kt + 1) * 32;
      gld16(xsrc + k0,   &xs[cur ^ 1][d0]);
      gld16(wasrc0 + k0, &was[cur ^ 1][d0]);
      gld16(wasrc1 + k0, &was[cur ^ 1][d1]);
      gld16(wbsrc0 + k0, &wbs[cur ^ 1][d0]);
      gld16(wbsrc1 + k0, &wbs[cur ^ 1][d1]);
    }
    bf16x8 af[4], ba[4], bb[4];
#pragma unroll
    for (int m = 0; m < 4; ++m)
      af[m] = *(const bf16x8*)&xs[cur][(wm * 64 + m * 16 + lr) * 32 + rslot];
#pragma unroll
    for (int n = 0; n < 4; ++n) {
      const int brow = (wn * 64 + n * 16 + lr) * 32 + rslot;
      ba[n] = *(const bf16x8*)&was[cur][brow];
      bb[n] = *(const bf16x8*)&wbs[cur][brow];
    }
#pragma unroll
    for (int m = 0; m < 4; ++m)
#pragma unroll
      for (int n = 0; n < 4; ++n) {
        aa[m][n] = __builtin_amdgcn_mfma_f32_16x16x32_bf16(af[m], ba[n], aa[m][n], 0, 0, 0);
        ab[m][n] = __builtin_amdgcn_mfma_f32_16x16x32_bf16(af[m], bb[n], ab[m][n], 0, 0, 0);
      }
    __syncthreads();
    cur ^= 1;
  }

  float b2av[4], b2bv[4], w30v[4], w31v[4];
#pragma unroll
  for (int n = 0; n < 4; ++n) {
    const int col = wn * 64 + n * 16 + lr;
    b2av[n] = b2a[col]; b2bv[n] = b2b[col];
    w30v[n] = W3[col];  w31v[n] = W3[256 + col];
  }
#pragma unroll
  for (int m = 0; m < 4; ++m) {
#pragma unroll
    for (int r = 0; r < 4; ++r) {
      float pm = 0.f, pl = 0.f;
#pragma unroll
      for (int n = 0; n < 4; ++n) {
        float a = 1.f / (1.f + __expf(-(aa[m][n][r] + b2av[n])));
        float b = tanhf(ab[m][n][r] + b2bv[n]);
        float p = a * b;
        pm += p * w30v[n];
        pl += p * w31v[n];
      }
#pragma unroll
      for (int d = 1; d < 16; d <<= 1) {
        pm += __shfl_xor(pm, d, 64);
        pl += __shfl_xor(pl, d, 64);
      }
      if (lr == 0) {
        pmu_s[wn][wm * 64 + m * 16 + g * 4 + r] = pm;
        plv_s[wn][wm * 64 + m * 16 + g * 4 + r] = pl;
      }
    }
  }
  __syncthreads();
  if (t < 128) {
    float mu = pmu_s[0][t] + pmu_s[1][t] + pmu_s[2][t] + pmu_s[3][t] + b3[0];
    float lv = plv_s[0][t] + plv_s[1][t] + plv_s[2][t] + plv_s[3][t] + b3[1];
    int row = rowBase + t;
    if (row < NPATCH) {
      int gx = coords[2 * row] >> 8;
      int gy = coords[2 * row + 1] >> 8;
      int cell = gy * GC + gx;
      mug[cell] = mu;
      lvg[cell] = lv;
    }
  }
}

// ---------------- K3: kl_div + gather-with-inline-conv + partial sums ----------------
__global__ __launch_bounds__(256) void patch_pass(
    const float* __restrict__ mug, const float* __restrict__ lvg,
    const float* __restrict__ eps, const float* __restrict__ kern,
    const int* __restrict__ slide, const int* __restrict__ coords,
    const unsigned short* __restrict__ xb, float* __restrict__ out_kl,
    float* __restrict__ out_pA, float* __restrict__ Mpart2,
    float* __restrict__ sumAp) {
  __shared__ float als[128];
  __shared__ float sred[2];
  const int t = threadIdx.x;
  const int base = blockIdx.x * 128;

  if (blockIdx.x < 256) {
    const int cell = blockIdx.x * 256 + t;
    const float mu = mug[cell], lv = lvg[cell];
    const int sl = slide[0];
    const float pm  = (sl == 0) ? -5.0f : 0.0f;
    const float plv = (sl == 0) ? -1.0f : 3.0f;
    const float d = pm - mu;
    out_kl[cell] = (plv - lv) * 0.5f + (lv * lv + d * d) / (2.0f * plv * plv) - 0.5f;
  }

  if (t < 128) {
    const int row = base + t;
    float a = 0.f;
    if (row < NPATCH) {
      const int gx = coords[2 * row] >> 8;
      const int gy = coords[2 * row + 1] >> 8;
      const int cell = gy * GC + gx;
      float s = 0.f;
#pragma unroll
      for (int dy = 0; dy < 3; ++dy) {
#pragma unroll
        for (int dx = 0; dx < 3; ++dx) {
          const int y = gy + dy - 1, x = gx + dx - 1;
          if (y >= 0 && y < GC && x >= 0 && x < GC)
            s += mug[y * GC + x] * kern[dy * 3 + dx];
        }
      }
      const float sample = s + eps[cell] * __expf(0.5f * lvg[cell]);
      a = 1.f / (1.f + __expf(-sample));
      out_pA[row] = a;
    }
    als[t] = a;
    float sa = a;
#pragma unroll
    for (int d = 1; d < 64; d <<= 1) sa += __shfl_xor(sa, d, 64);
    if ((t & 63) == 0) sred[t >> 6] = sa;
  }
  __syncthreads();
  if (t == 0) sumAp[blockIdx.x] = sred[0] + sred[1];

  int nrows = NPATCH - base;
  if (nrows > 128) nrows = 128;
  if (nrows < 0) nrows = 0;
  float m0 = 0.f, m1 = 0.f;
  for (int r = 0; r < nrows; ++r) {
    const float av = als[r];
    const uint32_t v = *(const uint32_t*)(xb + (size_t)(base + r) * 512 + t * 2);
    m0 += av * bf2f(v & 0xFFFFu);
    m1 += av * bf2f(v >> 16);
  }
  Mpart2[(size_t)blockIdx.x * 512 + 2 * t]     = m0;
  Mpart2[(size_t)blockIdx.x * 512 + 2 * t + 1] = m1;
}

// ---------------- K4: cross-block reduce + logits, softmax, argmax ----------------
__global__ __launch_bounds__(256) void finalize(
    const float* __restrict__ Mpart2, const float* __restrict__ sumAp,
    const float* __restrict__ Wc, const float* __restrict__ bc,
    float* __restrict__ out) {
  __shared__ float red0[4], red1[4], reds[4];
  const int t = threadIdx.x;
  const int c0 = 2 * t, c1 = 2 * t + 1;
  float m0 = 0.f, m1 = 0.f;
  for (int b = 0; b < 392; ++b) {
    m0 += Mpart2[(size_t)b * 512 + c0];
    m1 += Mpart2[(size_t)b * 512 + c1];
  }
  float sa = 0.f;
  if (t < 196) sa = sumAp[t] + ((t + 196 < 392) ? sumAp[t + 196] : 0.f);
#pragma unroll
  for (int d = 1; d < 64; d <<= 1) sa += __shfl_xor(sa, d, 64);
  if ((t & 63) == 0) reds[t >> 6] = sa;

  float l0 = m0 * Wc[c0] + m1 * Wc[c1];
  float l1 = m0 * Wc[512 + c0] + m1 * Wc[512 + c1];
#pragma unroll
  for (int d = 1; d < 64; d <<= 1) {
    l0 += __shfl_xor(l0, d, 64);
    l1 += __shfl_xor(l1, d, 64);
  }
  if ((t & 63) == 0) { red0[t >> 6] = l0; red1[t >> 6] = l1; }
  __syncthreads();
  if (t == 0) {
    const float s = reds[0] + reds[1] + reds[2] + reds[3];
    l0 = (red0[0] + red0[1] + red0[2] + red0[3]) / s + bc[0];
    l1 = (red1[0] + red1[1] + red1[2] + red1[3]) / s + bc[1];
    float mx = fmaxf(l0, l1);
    float e0 = __expf(l0 - mx), e1 = __expf(l1 - mx);
    float inv = 1.f / (e0 + e1);
    float p0 = e0 * inv, p1 = e1 * inv;
    out[0] = l0; out[1] = l1;
    out[2] = p0; out[3] = p1;
    out[4] = (l1 > l0) ? 1.0f : 0.0f;
    out[65541] = p0; out[65542] = p1;
  }
}

extern "C" void kernel_launch(void* const* d_in, const int* in_sizes, int n_in,
                              void* d_out, int out_size, void* d_ws, size_t ws_size,
                              hipStream_t stream) {
  const float* h      = (const float*)d_in[0];
  const int*   coords = (const int*)d_in[1];
  const float* eps    = (const float*)d_in[2];
  const float* W1     = (const float*)d_in[3];
  const float* b1     = (const float*)d_in[4];
  const float* W2a    = (const float*)d_in[5];
  const float* b2a    = (const float*)d_in[6];
  const float* W2b    = (const float*)d_in[7];
  const float* b2b    = (const float*)d_in[8];
  const float* W3     = (const float*)d_in[9];
  const float* b3     = (const float*)d_in[10];
  const float* Wc     = (const float*)d_in[11];
  const float* bc     = (const float*)d_in[12];
  const float* kern   = (const float*)d_in[13];
  const int*   slide  = (const int*)d_in[16];
  float* out = (float*)d_out;
  char*  ws  = (char*)d_ws;

  unsigned short* xb   = (unsigned short*)(ws + XB_OFF);
  unsigned short* W1b  = (unsigned short*)(ws + W1B_OFF);
  unsigned short* W2ab = (unsigned short*)(ws + W2AB_OFF);
  unsigned short* W2bb = (unsigned short*)(ws + W2BB_OFF);
  float* mug    = (float*)(ws + MUG_OFF);
  float* lvg    = (float*)(ws + LVG_OFF);
  float* Mpart2 = (float*)(ws + MPART2_OFF);
  float* sumAp  = (float*)(ws + SUMAP_OFF);

  convert_weights<<<2048, 256, 0, stream>>>(W1, W2a, W2b, W1b, W2ab, W2bb,
                                            (float*)(ws + MUG_OFF));
  gemm1<<<782, 256, 0, stream>>>(h, W1b, b1, xb);
  gemm2<<<391, 512, 0, stream>>>(xb, W2ab, W2bb, b2a, b2b, W3, b3, coords, mug, lvg);
  patch_pass<<<392, 256, 0, stream>>>(mug, lvg, eps, kern, slide, coords, xb,
                                      out + 5, out + 65543, Mpart2, sumAp);
  finalize<<<1, 256, 0, stream>>>(Mpart2, sumAp, Wc, bc, out);
}

// Round 22
// 179.466 us; speedup vs baseline: 1.0217x; 1.0111x over previous
//
#include <hip/hip_runtime.h>
#include <hip/hip_bf16.h>
#include <cstdint>
#include <cstddef>

#define NPATCH 50000
#define GC 256

typedef __bf16 bf16x8 __attribute__((ext_vector_type(8)));
typedef float  f32x4  __attribute__((ext_vector_type(4)));
typedef float  f32x8  __attribute__((ext_vector_type(8)));

// ---------------- workspace layout (bytes) ----------------
static constexpr size_t XB_OFF    = 0;                         // bf16 x [50048][512]
static constexpr size_t XB_BYTES  = (size_t)50048 * 512 * 2;
static constexpr size_t W1B_OFF   = XB_OFF + XB_BYTES;         // bf16 W1 [512][1024]
static constexpr size_t W1B_BYTES = (size_t)512 * 1024 * 2;
static constexpr size_t W2AB_OFF  = W1B_OFF + W1B_BYTES;       // bf16 W2a [256][512]
static constexpr size_t W2X_BYTES = (size_t)256 * 512 * 2;
static constexpr size_t W2BB_OFF  = W2AB_OFF + W2X_BYTES;      // bf16 W2b [256][512]
static constexpr size_t MUG_OFF   = W2BB_OFF + W2X_BYTES;      // f32 [65536]
static constexpr size_t LVG_OFF   = MUG_OFF + (size_t)65536 * 4;
static constexpr size_t AG_OFF    = LVG_OFF + (size_t)65536 * 4;  // (legacy, unused)
static constexpr size_t MPART_OFF = AG_OFF + (size_t)65536 * 4;   // (legacy, unused)
static constexpr size_t SUMA_OFF  = MPART_OFF + (size_t)512 * 4;
static constexpr size_t ZERO_BYTES = SUMA_OFF + 4 - MUG_OFF;   // zero mug..sumA
static constexpr int    ZERO_F32   = (int)(ZERO_BYTES / 4);    // 197121 floats
static constexpr size_t MPART2_OFF = ((SUMA_OFF + 4 + 63) / 64) * 64; // f32 [392][512]
static constexpr size_t SUMAP_OFF  = MPART2_OFF + (size_t)392 * 512 * 4; // f32 [392]

__device__ __forceinline__ unsigned short f2bf(float f) {
  union { float f; uint32_t u; } v; v.f = f;
  uint32_t u = v.u;
  uint32_t r = (u + 0x7FFFu + ((u >> 16) & 1u)) >> 16;
  return (unsigned short)r;
}
__device__ __forceinline__ float bf2f(uint32_t bits16) {
  union { uint32_t u; float f; } v; v.u = bits16 << 16; return v.f;
}
__device__ __forceinline__ unsigned short cvt_bf16(float f) {
  __bf16 b = (__bf16)f;
  return __builtin_bit_cast(unsigned short, b);
}
__device__ __forceinline__ void gld16(const void* g, void* l) {
  __builtin_amdgcn_global_load_lds(
      (const __attribute__((address_space(1))) void*)g,
      (__attribute__((address_space(3))) void*)l, 16, 0, 0);
}
__device__ __forceinline__ bf16x8 cvt8(const float4& f0, const float4& f1) {
  f32x8 fv;
  fv[0]=f0.x; fv[1]=f0.y; fv[2]=f0.z; fv[3]=f0.w;
  fv[4]=f1.x; fv[5]=f1.y; fv[6]=f1.z; fv[7]=f1.w;
  return __builtin_convertvector(fv, bf16x8);
}

// ---------------- K0: convert weights f32 -> bf16 + zero ws region ----------------
__global__ void convert_weights(const float* __restrict__ W1,
                                const float* __restrict__ W2a,
                                const float* __restrict__ W2b,
                                unsigned short* __restrict__ W1b,
                                unsigned short* __restrict__ W2ab,
                                unsigned short* __restrict__ W2bb,
                                float* __restrict__ zws) {
  int i = blockIdx.x * 256 + threadIdx.x;
  if (i < 512 * 1024) W1b[i] = f2bf(W1[i]);
  if (i < 256 * 512) { W2ab[i] = f2bf(W2a[i]); W2bb[i] = f2bf(W2b[i]); }
  if (i < ZERO_F32) zws[i] = 0.f;
}

// ---------------- K1: x = relu(h @ W1^T + b1) -> bf16 ----------------
// (final) 128x256 tile, BK=32, 256 threads = 4 waves (2M x 2N), per-wave
// 64x128 (acc[4][8]); 2 blocks/CU. P0 {af m0-3 + bf n0-3 + A ds_write(t+1)
// + A-loads(t+2); 16 MFMA}; P1 {bf n4-7 + B gld16(t+2) x4; 16 MFMA}.
// Boundary vmcnt(8) retires exactly B(t)x4 (full-tile cover). Swizzled LDS
// (0 conflicts); bijective XCD remap over 782 = 6*98 + 2*97 (m204).
__global__ __launch_bounds__(256, 2) void gemm1(
    const float* __restrict__ h, const unsigned short* __restrict__ W1b,
    const float* __restrict__ b1, unsigned short* __restrict__ xb) {
  __shared__ __align__(16) unsigned short lds[32768];  // 64 KB
  unsigned short* const A0 = lds;
  unsigned short* const A1 = lds + 4096;
  unsigned short* const B0 = lds + 8192;
  unsigned short* const B1 = lds + 16384;
  unsigned short* const B2 = lds + 24576;

  const int t  = threadIdx.x;
  const int l  = t & 63;
  const int w  = t >> 6;          // 0..3
  const int wm = w >> 1;          // 0..1 (64-row half)
  const int wn = w & 1;           // 0..1 (128-col half)
  const int g  = l >> 4;
  const int lr = l & 15;

  const int i   = blockIdx.x;
  const int xcd = i & 7;
  const int pos = i >> 3;
  const int v   = (xcd < 6 ? xcd * 98 : 6 * 98 + (xcd - 6) * 97) + pos;
  const int rt  = v >> 1;
  const int ct  = v & 1;
  const int rowBase = rt * 128;
  const int colBase = ct * 256;

  const int tr = t >> 1;
  const int hh = t & 1;
  int gr = rowBase + tr; if (gr >= NPATCH) gr = NPATCH - 1;
  const float* ah = h + (size_t)gr * 1024 + hh * 16;
  const int sw  = (tr >> 1) & 3;
  const int aw0 = tr * 32 + ((hh * 2)     ^ sw) * 8;
  const int aw1 = tr * 32 + ((hh * 2 + 1) ^ sw) * 8;

  const int bj = (t & 3) ^ ((t >> 3) & 3);
  const unsigned short* bh  = W1b + (size_t)(colBase + (t >> 2)) * 1024 + bj * 8;
  const unsigned short* bh2 = bh + (size_t)64 * 1024;
  const unsigned short* bh3 = bh + (size_t)128 * 1024;
  const unsigned short* bh4 = bh + (size_t)192 * 1024;
  const int bd = t * 8;

  const int rs = (g ^ ((lr >> 1) & 3)) * 8;
  const int abase = (wm * 64 + lr) * 32 + rs;
  const int bbase = (wn * 128 + lr) * 32 + rs;

  f32x4 acc[4][8];
#pragma unroll
  for (int m = 0; m < 4; ++m)
#pragma unroll
    for (int n = 0; n < 8; ++n) acc[m][n] = (f32x4){0.f, 0.f, 0.f, 0.f};

  unsigned short *pAr = A0, *pAw = A1;
  unsigned short *pBr = B0, *pBr1 = B1, *pBw = B2;

  float4 q0, q1, q2, q3;
  {
    gld16(bh,  pBr + bd);        gld16(bh2, pBr + 2048 + bd);
    gld16(bh3, pBr + 4096 + bd); gld16(bh4, pBr + 6144 + bd);
    float4 f0 = *(const float4*)(ah + 0);
    float4 f1 = *(const float4*)(ah + 4);
    float4 f2 = *(const float4*)(ah + 8);
    float4 f3 = *(const float4*)(ah + 12);
    *(bf16x8*)(pAr + aw0) = cvt8(f0, f1);
    *(bf16x8*)(pAr + aw1) = cvt8(f2, f3);
    q0 = *(const float4*)(ah + 32);
    q1 = *(const float4*)(ah + 36);
    q2 = *(const float4*)(ah + 40);
    q3 = *(const float4*)(ah + 44);
    gld16(bh + 32,  pBr1 + bd);        gld16(bh2 + 32, pBr1 + 2048 + bd);
    gld16(bh3 + 32, pBr1 + 4096 + bd); gld16(bh4 + 32, pBr1 + 6144 + bd);
  }
  asm volatile("s_waitcnt lgkmcnt(0)\n\ts_barrier" ::: "memory");

  for (int kt = 0; kt < 32; ++kt) {
    const int ka = ((kt + 2 <= 31) ? (kt + 2) : 31) * 32;
    bf16x8 af[4], bf[4];
#pragma unroll
    for (int m = 0; m < 4; ++m)
      af[m] = *(const bf16x8*)(pAr + abase + m * 512);
#pragma unroll
    for (int n = 0; n < 4; ++n)
      bf[n] = *(const bf16x8*)(pBr + bbase + n * 512);
    *(bf16x8*)(pAw + aw0) = cvt8(q0, q1);
    *(bf16x8*)(pAw + aw1) = cvt8(q2, q3);
    q0 = *(const float4*)(ah + ka + 0);
    q1 = *(const float4*)(ah + ka + 4);
    q2 = *(const float4*)(ah + ka + 8);
    q3 = *(const float4*)(ah + ka + 12);
    __builtin_amdgcn_sched_barrier(0);
    __builtin_amdgcn_s_barrier();
    __builtin_amdgcn_s_setprio(1);
#pragma unroll
    for (int m = 0; m < 4; ++m)
#pragma unroll
      for (int n = 0; n < 4; ++n)
        acc[m][n] = __builtin_amdgcn_mfma_f32_16x16x32_bf16(af[m], bf[n], acc[m][n], 0, 0, 0);
    __builtin_amdgcn_s_setprio(0);
    __builtin_amdgcn_s_barrier();
#pragma unroll
    for (int n = 0; n < 4; ++n)
      bf[n] = *(const bf16x8*)(pBr + bbase + (n + 4) * 512);
    gld16(bh + ka,  pBw + bd);        gld16(bh2 + ka, pBw + 2048 + bd);
    gld16(bh3 + ka, pBw + 4096 + bd); gld16(bh4 + ka, pBw + 6144 + bd);
    __builtin_amdgcn_sched_barrier(0);
    __builtin_amdgcn_s_barrier();
    __builtin_amdgcn_s_setprio(1);
#pragma unroll
    for (int m = 0; m < 4; ++m)
#pragma unroll
      for (int n = 0; n < 4; ++n)
        acc[m][n + 4] = __builtin_amdgcn_mfma_f32_16x16x32_bf16(af[m], bf[n], acc[m][n + 4], 0, 0, 0);
    __builtin_amdgcn_s_setprio(0);
    asm volatile("s_waitcnt vmcnt(8) lgkmcnt(0)\n\ts_barrier" ::: "memory");
    unsigned short* tA = pAr; pAr = pAw; pAw = tA;
    unsigned short* tB = pBr; pBr = pBr1; pBr1 = pBw; pBw = tB;
  }
  asm volatile("s_waitcnt vmcnt(0) lgkmcnt(0)" ::: "memory");

  float b1v[8];
#pragma unroll
  for (int n = 0; n < 8; ++n) b1v[n] = b1[colBase + wn * 128 + n * 16 + lr];
#pragma unroll
  for (int m = 0; m < 4; ++m) {
    const int rb0 = rowBase + wm * 64 + m * 16 + g * 4;
#pragma unroll
    for (int r = 0; r < 4; ++r) {
      const int row = rb0 + r;
      if (row < NPATCH) {
        unsigned short* xrow = xb + (size_t)row * 512 + colBase + wn * 128;
#pragma unroll
        for (int n = 0; n < 8; ++n) {
          float vv = acc[m][n][r] + b1v[n];
          vv = vv > 0.f ? vv : 0.f;
          xrow[n * 16 + lr] = cvt_bf16(vv);
        }
      }
    }
  }
}

// ---------------- K2: fa=sig(x@W2a^T+b2a), fb=tanh(x@W2b^T+b2b),
//                      params=(fa*fb)@W3^T+b3, scatter mu/logvar ----------------
__global__ __launch_bounds__(512) void gemm2(
    const unsigned short* __restrict__ xb,
    const unsigned short* __restrict__ W2ab, const unsigned short* __restrict__ W2bb,
    const float* __restrict__ b2a, const float* __restrict__ b2b,
    const float* __restrict__ W3, const float* __restrict__ b3,
    const int* __restrict__ coords,
    float* __restrict__ mug, float* __restrict__ lvg) {
  __shared__ __align__(16) unsigned short xs[2][128 * 32];   // 16 KB
  __shared__ __align__(16) unsigned short was[2][256 * 32];  // 32 KB
  __shared__ __align__(16) unsigned short wbs[2][256 * 32];  // 32 KB
  __shared__ float pmu_s[4][128];
  __shared__ float plv_s[4][128];

  const int t  = threadIdx.x;
  const int l  = t & 63;
  const int w  = t >> 6;
  const int wm = w >> 2;
  const int wn = w & 3;
  const int g  = l >> 4;
  const int lr = l & 15;
  const int rowBase = blockIdx.x * 128;

  const int bj = (t & 3) ^ ((t >> 3) & 3);
  const unsigned short* xsrc   = xb   + (size_t)(rowBase + (t >> 2)) * 512 + bj * 8;
  const unsigned short* wasrc0 = W2ab + (size_t)(t >> 2) * 512 + bj * 8;
  const unsigned short* wasrc1 = wasrc0 + (size_t)128 * 512;
  const unsigned short* wbsrc0 = W2bb + (size_t)(t >> 2) * 512 + bj * 8;
  const unsigned short* wbsrc1 = wbsrc0 + (size_t)128 * 512;
  const int d0 = t * 8;
  const int d1 = 4096 + t * 8;

  const int rslot = (g ^ ((lr >> 1) & 3)) * 8;

  f32x4 aa[4][4], ab[4][4];
#pragma unroll
  for (int m = 0; m < 4; ++m)
#pragma unroll
    for (int n = 0; n < 4; ++n) {
      aa[m][n] = (f32x4){0.f, 0.f, 0.f, 0.f};
      ab[m][n] = (f32x4){0.f, 0.f, 0.f, 0.f};
    }

  {
    gld16(xsrc,   &xs[0][d0]);
    gld16(wasrc0, &was[0][d0]);
    gld16(wasrc1, &was[0][d1]);
    gld16(wbsrc0, &wbs[0][d0]);
    gld16(wbsrc1, &wbs[0][d1]);
  }
  __syncthreads();

  int cur = 0;
  for (int kt = 0; kt < 16; ++kt) {
    if (kt < 15) {
      const int k0 = (kt + 1) * 32;
      gld16(xsrc + k0,   &xs[cur ^ 1][d0]);
      gld16(wasrc0 + k0, &was[cur ^ 1][d0]);
      gld16(wasrc1 + k0, &was[cur ^ 1][d1]);
      gld16(wbsrc0 + k0, &wbs[cur ^ 1][d0]);
      gld16(wbsrc1 + k0, &wbs[cur ^ 1][d1]);
    }
    bf16x8 af[4], ba[4], bb[4];
#pragma unroll
    for (int m = 0; m < 4; ++m)
      af[m] = *(const bf16x8*)&xs[cur][(wm * 64 + m * 16 + lr) * 32 + rslot];
#pragma unroll
    for (int n = 0; n < 4; ++n) {
      const int brow = (wn * 64 + n * 16 + lr) * 32 + rslot;
      ba[n] = *(const bf16x8*)&was[cur][brow];
      bb[n] = *(const bf16x8*)&wbs[cur][brow];
    }
#pragma unroll
    for (int m = 0; m < 4; ++m)
#pragma unroll
      for (int n = 0; n < 4; ++n) {
        aa[m][n] = __builtin_amdgcn_mfma_f32_16x16x32_bf16(af[m], ba[n], aa[m][n], 0, 0, 0);
        ab[m][n] = __builtin_amdgcn_mfma_f32_16x16x32_bf16(af[m], bb[n], ab[m][n], 0, 0, 0);
      }
    __syncthreads();
    cur ^= 1;
  }

  float b2av[4], b2bv[4], w30v[4], w31v[4];
#pragma unroll
  for (int n = 0; n < 4; ++n) {
    const int col = wn * 64 + n * 16 + lr;
    b2av[n] = b2a[col]; b2bv[n] = b2b[col];
    w30v[n] = W3[col];  w31v[n] = W3[256 + col];
  }
#pragma unroll
  for (int m = 0; m < 4; ++m) {
#pragma unroll
    for (int r = 0; r < 4; ++r) {
      float pm = 0.f, pl = 0.f;
#pragma unroll
      for (int n = 0; n < 4; ++n) {
        float a = 1.f / (1.f + __expf(-(aa[m][n][r] + b2av[n])));
        float b = tanhf(ab[m][n][r] + b2bv[n]);
        float p = a * b;
        pm += p * w30v[n];
        pl += p * w31v[n];
      }
#pragma unroll
      for (int d = 1; d < 16; d <<= 1) {
        pm += __shfl_xor(pm, d, 64);
        pl += __shfl_xor(pl, d, 64);
      }
      if (lr == 0) {
        pmu_s[wn][wm * 64 + m * 16 + g * 4 + r] = pm;
        plv_s[wn][wm * 64 + m * 16 + g * 4 + r] = pl;
      }
    }
  }
  __syncthreads();
  if (t < 128) {
    float mu = pmu_s[0][t] + pmu_s[1][t] + pmu_s[2][t] + pmu_s[3][t] + b3[0];
    float lv = plv_s[0][t] + plv_s[1][t] + plv_s[2][t] + plv_s[3][t] + b3[1];
    int row = rowBase + t;
    if (row < NPATCH) {
      int gx = coords[2 * row] >> 8;
      int gy = coords[2 * row + 1] >> 8;
      int cell = gy * GC + gx;
      mug[cell] = mu;
      lvg[cell] = lv;
    }
  }
}

// ---------------- K3: kl_div + gather-with-inline-conv + partial sums ----------------
__global__ __launch_bounds__(256) void patch_pass(
    const float* __restrict__ mug, const float* __restrict__ lvg,
    const float* __restrict__ eps, const float* __restrict__ kern,
    const int* __restrict__ slide, const int* __restrict__ coords,
    const unsigned short* __restrict__ xb, float* __restrict__ out_kl,
    float* __restrict__ out_pA, float* __restrict__ Mpart2,
    float* __restrict__ sumAp) {
  __shared__ float als[128];
  __shared__ float sred[2];
  const int t = threadIdx.x;
  const int base = blockIdx.x * 128;

  if (blockIdx.x < 256) {
    const int cell = blockIdx.x * 256 + t;
    const float mu = mug[cell], lv = lvg[cell];
    const int sl = slide[0];
    const float pm  = (sl == 0) ? -5.0f : 0.0f;
    const float plv = (sl == 0) ? -1.0f : 3.0f;
    const float d = pm - mu;
    out_kl[cell] = (plv - lv) * 0.5f + (lv * lv + d * d) / (2.0f * plv * plv) - 0.5f;
  }

  if (t < 128) {
    const int row = base + t;
    float a = 0.f;
    if (row < NPATCH) {
      const int gx = coords[2 * row] >> 8;
      const int gy = coords[2 * row + 1] >> 8;
      const int cell = gy * GC + gx;
      float s = 0.f;
#pragma unroll
      for (int dy = 0; dy < 3; ++dy) {
#pragma unroll
        for (int dx = 0; dx < 3; ++dx) {
          const int y = gy + dy - 1, x = gx + dx - 1;
          if (y >= 0 && y < GC && x >= 0 && x < GC)
            s += mug[y * GC + x] * kern[dy * 3 + dx];
        }
      }
      const float sample = s + eps[cell] * __expf(0.5f * lvg[cell]);
      a = 1.f / (1.f + __expf(-sample));
      out_pA[row] = a;
    }
    als[t] = a;
    float sa = a;
#pragma unroll
    for (int d = 1; d < 64; d <<= 1) sa += __shfl_xor(sa, d, 64);
    if ((t & 63) == 0) sred[t >> 6] = sa;
  }
  __syncthreads();
  if (t == 0) sumAp[blockIdx.x] = sred[0] + sred[1];

  int nrows = NPATCH - base;
  if (nrows > 128) nrows = 128;
  if (nrows < 0) nrows = 0;
  float m0 = 0.f, m1 = 0.f;
  for (int r = 0; r < nrows; ++r) {
    const float av = als[r];
    const uint32_t v = *(const uint32_t*)(xb + (size_t)(base + r) * 512 + t * 2);
    m0 += av * bf2f(v & 0xFFFFu);
    m1 += av * bf2f(v >> 16);
  }
  Mpart2[(size_t)blockIdx.x * 512 + 2 * t]     = m0;
  Mpart2[(size_t)blockIdx.x * 512 + 2 * t + 1] = m1;
}

// ---------------- K4: cross-block reduce + logits, softmax, argmax ----------------
__global__ __launch_bounds__(256) void finalize(
    const float* __restrict__ Mpart2, const float* __restrict__ sumAp,
    const float* __restrict__ Wc, const float* __restrict__ bc,
    float* __restrict__ out) {
  __shared__ float red0[4], red1[4], reds[4];
  const int t = threadIdx.x;
  const int c0 = 2 * t, c1 = 2 * t + 1;
  float m0 = 0.f, m1 = 0.f;
  for (int b = 0; b < 392; ++b) {
    m0 += Mpart2[(size_t)b * 512 + c0];
    m1 += Mpart2[(size_t)b * 512 + c1];
  }
  float sa = 0.f;
  if (t < 196) sa = sumAp[t] + ((t + 196 < 392) ? sumAp[t + 196] : 0.f);
#pragma unroll
  for (int d = 1; d < 64; d <<= 1) sa += __shfl_xor(sa, d, 64);
  if ((t & 63) == 0) reds[t >> 6] = sa;

  float l0 = m0 * Wc[c0] + m1 * Wc[c1];
  float l1 = m0 * Wc[512 + c0] + m1 * Wc[512 + c1];
#pragma unroll
  for (int d = 1; d < 64; d <<= 1) {
    l0 += __shfl_xor(l0, d, 64);
    l1 += __shfl_xor(l1, d, 64);
  }
  if ((t & 63) == 0) { red0[t >> 6] = l0; red1[t >> 6] = l1; }
  __syncthreads();
  if (t == 0) {
    const float s = reds[0] + reds[1] + reds[2] + reds[3];
    l0 = (red0[0] + red0[1] + red0[2] + red0[3]) / s + bc[0];
    l1 = (red1[0] + red1[1] + red1[2] + red1[3]) / s + bc[1];
    float mx = fmaxf(l0, l1);
    float e0 = __expf(l0 - mx), e1 = __expf(l1 - mx);
    float inv = 1.f / (e0 + e1);
    float p0 = e0 * inv, p1 = e1 * inv;
    out[0] = l0; out[1] = l1;
    out[2] = p0; out[3] = p1;
    out[4] = (l1 > l0) ? 1.0f : 0.0f;
    out[65541] = p0; out[65542] = p1;
  }
}

extern "C" void kernel_launch(void* const* d_in, const int* in_sizes, int n_in,
                              void* d_out, int out_size, void* d_ws, size_t ws_size,
                              hipStream_t stream) {
  const float* h      = (const float*)d_in[0];
  const int*   coords = (const int*)d_in[1];
  const float* eps    = (const float*)d_in[2];
  const float* W1     = (const float*)d_in[3];
  const float* b1     = (const float*)d_in[4];
  const float* W2a    = (const float*)d_in[5];
  const float* b2a    = (const float*)d_in[6];
  const float* W2b    = (const float*)d_in[7];
  const float* b2b    = (const float*)d_in[8];
  const float* W3     = (const float*)d_in[9];
  const float* b3     = (const float*)d_in[10];
  const float* Wc     = (const float*)d_in[11];
  const float* bc     = (const float*)d_in[12];
  const float* kern   = (const float*)d_in[13];
  const int*   slide  = (const int*)d_in[16];
  float* out = (float*)d_out;
  char*  ws  = (char*)d_ws;

  unsigned short* xb   = (unsigned short*)(ws + XB_OFF);
  unsigned short* W1b  = (unsigned short*)(ws + W1B_OFF);
  unsigned short* W2ab = (unsigned short*)(ws + W2AB_OFF);
  unsigned short* W2bb = (unsigned short*)(ws + W2BB_OFF);
  float* mug    = (float*)(ws + MUG_OFF);
  float* lvg    = (float*)(ws + LVG_OFF);
  float* Mpart2 = (float*)(ws + MPART2_OFF);
  float* sumAp  = (float*)(ws + SUMAP_OFF);

  convert_weights<<<2048, 256, 0, stream>>>(W1, W2a, W2b, W1b, W2ab, W2bb,
                                            (float*)(ws + MUG_OFF));
  gemm1<<<782, 256, 0, stream>>>(h, W1b, b1, xb);
  gemm2<<<391, 512, 0, stream>>>(xb, W2ab, W2bb, b2a, b2b, W3, b3, coords, mug, lvg);
  patch_pass<<<392, 256, 0, stream>>>(mug, lvg, eps, kern, slide, coords, xb,
                                      out + 5, out + 65543, Mpart2, sumAp);
  finalize<<<1, 256, 0, stream>>>(Mpart2, sumAp, Wc, bc, out);
}

// Round 23
// 179.267 us; speedup vs baseline: 1.0229x; 1.0011x over previous
//
#include <hip/hip_runtime.h>
#include <hip/hip_bf16.h>
#include <cstdint>
#include <cstddef>

#define NPATCH 50000
#define GC 256

typedef __bf16 bf16x8 __attribute__((ext_vector_type(8)));
typedef float  f32x4  __attribute__((ext_vector_type(4)));
typedef float  f32x8  __attribute__((ext_vector_type(8)));

// ---------------- workspace layout (bytes) ----------------
static constexpr size_t XB_OFF    = 0;                         // bf16 x [50048][512]
static constexpr size_t XB_BYTES  = (size_t)50048 * 512 * 2;
static constexpr size_t W1B_OFF   = XB_OFF + XB_BYTES;         // bf16 W1 [512][1024]
static constexpr size_t W1B_BYTES = (size_t)512 * 1024 * 2;
static constexpr size_t W2AB_OFF  = W1B_OFF + W1B_BYTES;       // bf16 W2a [256][512]
static constexpr size_t W2X_BYTES = (size_t)256 * 512 * 2;
static constexpr size_t W2BB_OFF  = W2AB_OFF + W2X_BYTES;      // bf16 W2b [256][512]
static constexpr size_t MUG_OFF   = W2BB_OFF + W2X_BYTES;      // f32 [65536]
static constexpr size_t LVG_OFF   = MUG_OFF + (size_t)65536 * 4;
static constexpr size_t AG_OFF    = LVG_OFF + (size_t)65536 * 4;  // (legacy, unused)
static constexpr size_t MPART_OFF = AG_OFF + (size_t)65536 * 4;   // (legacy, unused)
static constexpr size_t SUMA_OFF  = MPART_OFF + (size_t)512 * 4;
static constexpr size_t ZERO_BYTES = SUMA_OFF + 4 - MUG_OFF;   // zero mug..sumA
static constexpr int    ZERO_F32   = (int)(ZERO_BYTES / 4);    // 197121 floats
static constexpr size_t MPART2_OFF = ((SUMA_OFF + 4 + 63) / 64) * 64; // f32 [392][512]
static constexpr size_t SUMAP_OFF  = MPART2_OFF + (size_t)392 * 512 * 4; // f32 [392]

__device__ __forceinline__ unsigned short f2bf(float f) {
  union { float f; uint32_t u; } v; v.f = f;
  uint32_t u = v.u;
  uint32_t r = (u + 0x7FFFu + ((u >> 16) & 1u)) >> 16;
  return (unsigned short)r;
}
__device__ __forceinline__ float bf2f(uint32_t bits16) {
  union { uint32_t u; float f; } v; v.u = bits16 << 16; return v.f;
}
__device__ __forceinline__ unsigned short cvt_bf16(float f) {
  __bf16 b = (__bf16)f;
  return __builtin_bit_cast(unsigned short, b);
}
__device__ __forceinline__ void gld16(const void* g, void* l) {
  __builtin_amdgcn_global_load_lds(
      (const __attribute__((address_space(1))) void*)g,
      (__attribute__((address_space(3))) void*)l, 16, 0, 0);
}
__device__ __forceinline__ bf16x8 cvt8(const float4& f0, const float4& f1) {
  f32x8 fv;
  fv[0]=f0.x; fv[1]=f0.y; fv[2]=f0.z; fv[3]=f0.w;
  fv[4]=f1.x; fv[5]=f1.y; fv[6]=f1.z; fv[7]=f1.w;
  return __builtin_convertvector(fv, bf16x8);
}

// ---------------- K0: convert weights f32 -> bf16 + zero ws region ----------------
__global__ void convert_weights(const float* __restrict__ W1,
                                const float* __restrict__ W2a,
                                const float* __restrict__ W2b,
                                unsigned short* __restrict__ W1b,
                                unsigned short* __restrict__ W2ab,
                                unsigned short* __restrict__ W2bb,
                                float* __restrict__ zws) {
  int i = blockIdx.x * 256 + threadIdx.x;
  if (i < 512 * 1024) W1b[i] = f2bf(W1[i]);
  if (i < 256 * 512) { W2ab[i] = f2bf(W2a[i]); W2bb[i] = f2bf(W2b[i]); }
  if (i < ZERO_F32) zws[i] = 0.f;
}

// ---------------- K1: x = relu(h @ W1^T + b1) -> bf16 ----------------
// (final) 128x256 tile, BK=32, 256 threads = 4 waves (2M x 2N), per-wave
// 64x128 (acc[4][8]); 2 blocks/CU. P0 {af m0-3 + bf n0-3 + A ds_write(t+1)
// + A-loads(t+2); 16 MFMA}; P1 {bf n4-7 + B gld16(t+2) x4; 16 MFMA}.
// Boundary vmcnt(8) retires exactly B(t)x4 (full-tile cover). Swizzled LDS
// (0 conflicts); bijective XCD remap over 782 = 6*98 + 2*97 (m204).
__global__ __launch_bounds__(256, 2) void gemm1(
    const float* __restrict__ h, const unsigned short* __restrict__ W1b,
    const float* __restrict__ b1, unsigned short* __restrict__ xb) {
  __shared__ __align__(16) unsigned short lds[32768];  // 64 KB
  unsigned short* const A0 = lds;
  unsigned short* const A1 = lds + 4096;
  unsigned short* const B0 = lds + 8192;
  unsigned short* const B1 = lds + 16384;
  unsigned short* const B2 = lds + 24576;

  const int t  = threadIdx.x;
  const int l  = t & 63;
  const int w  = t >> 6;          // 0..3
  const int wm = w >> 1;          // 0..1 (64-row half)
  const int wn = w & 1;           // 0..1 (128-col half)
  const int g  = l >> 4;
  const int lr = l & 15;

  const int i   = blockIdx.x;
  const int xcd = i & 7;
  const int pos = i >> 3;
  const int v   = (xcd < 6 ? xcd * 98 : 6 * 98 + (xcd - 6) * 97) + pos;
  const int rt  = v >> 1;
  const int ct  = v & 1;
  const int rowBase = rt * 128;
  const int colBase = ct * 256;

  const int tr = t >> 1;
  const int hh = t & 1;
  int gr = rowBase + tr; if (gr >= NPATCH) gr = NPATCH - 1;
  const float* ah = h + (size_t)gr * 1024 + hh * 16;
  const int sw  = (tr >> 1) & 3;
  const int aw0 = tr * 32 + ((hh * 2)     ^ sw) * 8;
  const int aw1 = tr * 32 + ((hh * 2 + 1) ^ sw) * 8;

  const int bj = (t & 3) ^ ((t >> 3) & 3);
  const unsigned short* bh  = W1b + (size_t)(colBase + (t >> 2)) * 1024 + bj * 8;
  const unsigned short* bh2 = bh + (size_t)64 * 1024;
  const unsigned short* bh3 = bh + (size_t)128 * 1024;
  const unsigned short* bh4 = bh + (size_t)192 * 1024;
  const int bd = t * 8;

  const int rs = (g ^ ((lr >> 1) & 3)) * 8;
  const int abase = (wm * 64 + lr) * 32 + rs;
  const int bbase = (wn * 128 + lr) * 32 + rs;

  f32x4 acc[4][8];
#pragma unroll
  for (int m = 0; m < 4; ++m)
#pragma unroll
    for (int n = 0; n < 8; ++n) acc[m][n] = (f32x4){0.f, 0.f, 0.f, 0.f};

  unsigned short *pAr = A0, *pAw = A1;
  unsigned short *pBr = B0, *pBr1 = B1, *pBw = B2;

  float4 q0, q1, q2, q3;
  {
    gld16(bh,  pBr + bd);        gld16(bh2, pBr + 2048 + bd);
    gld16(bh3, pBr + 4096 + bd); gld16(bh4, pBr + 6144 + bd);
    float4 f0 = *(const float4*)(ah + 0);
    float4 f1 = *(const float4*)(ah + 4);
    float4 f2 = *(const float4*)(ah + 8);
    float4 f3 = *(const float4*)(ah + 12);
    *(bf16x8*)(pAr + aw0) = cvt8(f0, f1);
    *(bf16x8*)(pAr + aw1) = cvt8(f2, f3);
    q0 = *(const float4*)(ah + 32);
    q1 = *(const float4*)(ah + 36);
    q2 = *(const float4*)(ah + 40);
    q3 = *(const float4*)(ah + 44);
    gld16(bh + 32,  pBr1 + bd);        gld16(bh2 + 32, pBr1 + 2048 + bd);
    gld16(bh3 + 32, pBr1 + 4096 + bd); gld16(bh4 + 32, pBr1 + 6144 + bd);
  }
  asm volatile("s_waitcnt lgkmcnt(0)\n\ts_barrier" ::: "memory");

  for (int kt = 0; kt < 32; ++kt) {
    const int ka = ((kt + 2 <= 31) ? (kt + 2) : 31) * 32;
    bf16x8 af[4], bf[4];
#pragma unroll
    for (int m = 0; m < 4; ++m)
      af[m] = *(const bf16x8*)(pAr + abase + m * 512);
#pragma unroll
    for (int n = 0; n < 4; ++n)
      bf[n] = *(const bf16x8*)(pBr + bbase + n * 512);
    *(bf16x8*)(pAw + aw0) = cvt8(q0, q1);
    *(bf16x8*)(pAw + aw1) = cvt8(q2, q3);
    q0 = *(const float4*)(ah + ka + 0);
    q1 = *(const float4*)(ah + ka + 4);
    q2 = *(const float4*)(ah + ka + 8);
    q3 = *(const float4*)(ah + ka + 12);
    __builtin_amdgcn_sched_barrier(0);
    __builtin_amdgcn_s_barrier();
    __builtin_amdgcn_s_setprio(1);
#pragma unroll
    for (int m = 0; m < 4; ++m)
#pragma unroll
      for (int n = 0; n < 4; ++n)
        acc[m][n] = __builtin_amdgcn_mfma_f32_16x16x32_bf16(af[m], bf[n], acc[m][n], 0, 0, 0);
    __builtin_amdgcn_s_setprio(0);
    __builtin_amdgcn_s_barrier();
#pragma unroll
    for (int n = 0; n < 4; ++n)
      bf[n] = *(const bf16x8*)(pBr + bbase + (n + 4) * 512);
    gld16(bh + ka,  pBw + bd);        gld16(bh2 + ka, pBw + 2048 + bd);
    gld16(bh3 + ka, pBw + 4096 + bd); gld16(bh4 + ka, pBw + 6144 + bd);
    __builtin_amdgcn_sched_barrier(0);
    __builtin_amdgcn_s_barrier();
    __builtin_amdgcn_s_setprio(1);
#pragma unroll
    for (int m = 0; m < 4; ++m)
#pragma unroll
      for (int n = 0; n < 4; ++n)
        acc[m][n + 4] = __builtin_amdgcn_mfma_f32_16x16x32_bf16(af[m], bf[n], acc[m][n + 4], 0, 0, 0);
    __builtin_amdgcn_s_setprio(0);
    asm volatile("s_waitcnt vmcnt(8) lgkmcnt(0)\n\ts_barrier" ::: "memory");
    unsigned short* tA = pAr; pAr = pAw; pAw = tA;
    unsigned short* tB = pBr; pBr = pBr1; pBr1 = pBw; pBw = tB;
  }
  asm volatile("s_waitcnt vmcnt(0) lgkmcnt(0)" ::: "memory");

  float b1v[8];
#pragma unroll
  for (int n = 0; n < 8; ++n) b1v[n] = b1[colBase + wn * 128 + n * 16 + lr];
#pragma unroll
  for (int m = 0; m < 4; ++m) {
    const int rb0 = rowBase + wm * 64 + m * 16 + g * 4;
#pragma unroll
    for (int r = 0; r < 4; ++r) {
      const int row = rb0 + r;
      if (row < NPATCH) {
        unsigned short* xrow = xb + (size_t)row * 512 + colBase + wn * 128;
#pragma unroll
        for (int n = 0; n < 8; ++n) {
          float vv = acc[m][n][r] + b1v[n];
          vv = vv > 0.f ? vv : 0.f;
          xrow[n * 16 + lr] = cvt_bf16(vv);
        }
      }
    }
  }
}

// ---------------- K2: fa=sig(x@W2a^T+b2a), fb=tanh(x@W2b^T+b2b),
//                      params=(fa*fb)@W3^T+b3, scatter mu/logvar ----------------
__global__ __launch_bounds__(512) void gemm2(
    const unsigned short* __restrict__ xb,
    const unsigned short* __restrict__ W2ab, const unsigned short* __restrict__ W2bb,
    const float* __restrict__ b2a, const float* __restrict__ b2b,
    const float* __restrict__ W3, const float* __restrict__ b3,
    const int* __restrict__ coords,
    float* __restrict__ mug, float* __restrict__ lvg) {
  __shared__ __align__(16) unsigned short xs[2][128 * 32];   // 16 KB
  __shared__ __align__(16) unsigned short was[2][256 * 32];  // 32 KB
  __shared__ __align__(16) unsigned short wbs[2][256 * 32];  // 32 KB
  __shared__ float pmu_s[4][128];
  __shared__ float plv_s[4][128];

  const int t  = threadIdx.x;
  const int l  = t & 63;
  const int w  = t >> 6;
  const int wm = w >> 2;
  const int wn = w & 3;
  const int g  = l >> 4;
  const int lr = l & 15;
  const int rowBase = blockIdx.x * 128;

  const int bj = (t & 3) ^ ((t >> 3) & 3);
  const unsigned short* xsrc   = xb   + (size_t)(rowBase + (t >> 2)) * 512 + bj * 8;
  const unsigned short* wasrc0 = W2ab + (size_t)(t >> 2) * 512 + bj * 8;
  const unsigned short* wasrc1 = wasrc0 + (size_t)128 * 512;
  const unsigned short* wbsrc0 = W2bb + (size_t)(t >> 2) * 512 + bj * 8;
  const unsigned short* wbsrc1 = wbsrc0 + (size_t)128 * 512;
  const int d0 = t * 8;
  const int d1 = 4096 + t * 8;

  const int rslot = (g ^ ((lr >> 1) & 3)) * 8;

  f32x4 aa[4][4], ab[4][4];
#pragma unroll
  for (int m = 0; m < 4; ++m)
#pragma unroll
    for (int n = 0; n < 4; ++n) {
      aa[m][n] = (f32x4){0.f, 0.f, 0.f, 0.f};
      ab[m][n] = (f32x4){0.f, 0.f, 0.f, 0.f};
    }

  {
    gld16(xsrc,   &xs[0][d0]);
    gld16(wasrc0, &was[0][d0]);
    gld16(wasrc1, &was[0][d1]);
    gld16(wbsrc0, &wbs[0][d0]);
    gld16(wbsrc1, &wbs[0][d1]);
  }
  __syncthreads();

  int cur = 0;
  for (int kt = 0; kt < 16; ++kt) {
    if (kt < 15) {
      const int k0 = (kt + 1) * 32;
      gld16(xsrc + k0,   &xs[cur ^ 1][d0]);
      gld16(wasrc0 + k0, &was[cur ^ 1][d0]);
      gld16(wasrc1 + k0, &was[cur ^ 1][d1]);
      gld16(wbsrc0 + k0, &wbs[cur ^ 1][d0]);
      gld16(wbsrc1 + k0, &wbs[cur ^ 1][d1]);
    }
    bf16x8 af[4], ba[4], bb[4];
#pragma unroll
    for (int m = 0; m < 4; ++m)
      af[m] = *(const bf16x8*)&xs[cur][(wm * 64 + m * 16 + lr) * 32 + rslot];
#pragma unroll
    for (int n = 0; n < 4; ++n) {
      const int brow = (wn * 64 + n * 16 + lr) * 32 + rslot;
      ba[n] = *(const bf16x8*)&was[cur][brow];
      bb[n] = *(const bf16x8*)&wbs[cur][brow];
    }
#pragma unroll
    for (int m = 0; m < 4; ++m)
#pragma unroll
      for (int n = 0; n < 4; ++n) {
        aa[m][n] = __builtin_amdgcn_mfma_f32_16x16x32_bf16(af[m], ba[n], aa[m][n], 0, 0, 0);
        ab[m][n] = __builtin_amdgcn_mfma_f32_16x16x32_bf16(af[m], bb[n], ab[m][n], 0, 0, 0);
      }
    __syncthreads();
    cur ^= 1;
  }

  float b2av[4], b2bv[4], w30v[4], w31v[4];
#pragma unroll
  for (int n = 0; n < 4; ++n) {
    const int col = wn * 64 + n * 16 + lr;
    b2av[n] = b2a[col]; b2bv[n] = b2b[col];
    w30v[n] = W3[col];  w31v[n] = W3[256 + col];
  }
#pragma unroll
  for (int m = 0; m < 4; ++m) {
#pragma unroll
    for (int r = 0; r < 4; ++r) {
      float pm = 0.f, pl = 0.f;
#pragma unroll
      for (int n = 0; n < 4; ++n) {
        float a = 1.f / (1.f + __expf(-(aa[m][n][r] + b2av[n])));
        float b = tanhf(ab[m][n][r] + b2bv[n]);
        float p = a * b;
        pm += p * w30v[n];
        pl += p * w31v[n];
      }
#pragma unroll
      for (int d = 1; d < 16; d <<= 1) {
        pm += __shfl_xor(pm, d, 64);
        pl += __shfl_xor(pl, d, 64);
      }
      if (lr == 0) {
        pmu_s[wn][wm * 64 + m * 16 + g * 4 + r] = pm;
        plv_s[wn][wm * 64 + m * 16 + g * 4 + r] = pl;
      }
    }
  }
  __syncthreads();
  if (t < 128) {
    float mu = pmu_s[0][t] + pmu_s[1][t] + pmu_s[2][t] + pmu_s[3][t] + b3[0];
    float lv = plv_s[0][t] + plv_s[1][t] + plv_s[2][t] + plv_s[3][t] + b3[1];
    int row = rowBase + t;
    if (row < NPATCH) {
      int gx = coords[2 * row] >> 8;
      int gy = coords[2 * row + 1] >> 8;
      int cell = gy * GC + gx;
      mug[cell] = mu;
      lvg[cell] = lv;
    }
  }
}

// ---------------- K3: kl_div + gather-with-inline-conv + partial sums ----------------
__global__ __launch_bounds__(256) void patch_pass(
    const float* __restrict__ mug, const float* __restrict__ lvg,
    const float* __restrict__ eps, const float* __restrict__ kern,
    const int* __restrict__ slide, const int* __restrict__ coords,
    const unsigned short* __restrict__ xb, float* __restrict__ out_kl,
    float* __restrict__ out_pA, float* __restrict__ Mpart2,
    float* __restrict__ sumAp) {
  __shared__ float als[128];
  __shared__ float sred[2];
  const int t = threadIdx.x;
  const int base = blockIdx.x * 128;

  if (blockIdx.x < 256) {
    const int cell = blockIdx.x * 256 + t;
    const float mu = mug[cell], lv = lvg[cell];
    const int sl = slide[0];
    const float pm  = (sl == 0) ? -5.0f : 0.0f;
    const float plv = (sl == 0) ? -1.0f : 3.0f;
    const float d = pm - mu;
    out_kl[cell] = (plv - lv) * 0.5f + (lv * lv + d * d) / (2.0f * plv * plv) - 0.5f;
  }

  if (t < 128) {
    const int row = base + t;
    float a = 0.f;
    if (row < NPATCH) {
      const int gx = coords[2 * row] >> 8;
      const int gy = coords[2 * row + 1] >> 8;
      const int cell = gy * GC + gx;
      float s = 0.f;
#pragma unroll
      for (int dy = 0; dy < 3; ++dy) {
#pragma unroll
        for (int dx = 0; dx < 3; ++dx) {
          const int y = gy + dy - 1, x = gx + dx - 1;
          if (y >= 0 && y < GC && x >= 0 && x < GC)
            s += mug[y * GC + x] * kern[dy * 3 + dx];
        }
      }
      const float sample = s + eps[cell] * __expf(0.5f * lvg[cell]);
      a = 1.f / (1.f + __expf(-sample));
      out_pA[row] = a;
    }
    als[t] = a;
    float sa = a;
#pragma unroll
    for (int d = 1; d < 64; d <<= 1) sa += __shfl_xor(sa, d, 64);
    if ((t & 63) == 0) sred[t >> 6] = sa;
  }
  __syncthreads();
  if (t == 0) sumAp[blockIdx.x] = sred[0] + sred[1];

  int nrows = NPATCH - base;
  if (nrows > 128) nrows = 128;
  if (nrows < 0) nrows = 0;
  float m0 = 0.f, m1 = 0.f;
  for (int r = 0; r < nrows; ++r) {
    const float av = als[r];
    const uint32_t v = *(const uint32_t*)(xb + (size_t)(base + r) * 512 + t * 2);
    m0 += av * bf2f(v & 0xFFFFu);
    m1 += av * bf2f(v >> 16);
  }
  Mpart2[(size_t)blockIdx.x * 512 + 2 * t]     = m0;
  Mpart2[(size_t)blockIdx.x * 512 + 2 * t + 1] = m1;
}

// ---------------- K4: cross-block reduce + logits, softmax, argmax ----------------
__global__ __launch_bounds__(256) void finalize(
    const float* __restrict__ Mpart2, const float* __restrict__ sumAp,
    const float* __restrict__ Wc, const float* __restrict__ bc,
    float* __restrict__ out) {
  __shared__ float red0[4], red1[4], reds[4];
  const int t = threadIdx.x;
  const int c0 = 2 * t, c1 = 2 * t + 1;
  float m0 = 0.f, m1 = 0.f;
  for (int b = 0; b < 392; ++b) {
    m0 += Mpart2[(size_t)b * 512 + c0];
    m1 += Mpart2[(size_t)b * 512 + c1];
  }
  float sa = 0.f;
  if (t < 196) sa = sumAp[t] + ((t + 196 < 392) ? sumAp[t + 196] : 0.f);
#pragma unroll
  for (int d = 1; d < 64; d <<= 1) sa += __shfl_xor(sa, d, 64);
  if ((t & 63) == 0) reds[t >> 6] = sa;

  float l0 = m0 * Wc[c0] + m1 * Wc[c1];
  float l1 = m0 * Wc[512 + c0] + m1 * Wc[512 + c1];
#pragma unroll
  for (int d = 1; d < 64; d <<= 1) {
    l0 += __shfl_xor(l0, d, 64);
    l1 += __shfl_xor(l1, d, 64);
  }
  if ((t & 63) == 0) { red0[t >> 6] = l0; red1[t >> 6] = l1; }
  __syncthreads();
  if (t == 0) {
    const float s = reds[0] + reds[1] + reds[2] + reds[3];
    l0 = (red0[0] + red0[1] + red0[2] + red0[3]) / s + bc[0];
    l1 = (red1[0] + red1[1] + red1[2] + red1[3]) / s + bc[1];
    float mx = fmaxf(l0, l1);
    float e0 = __expf(l0 - mx), e1 = __expf(l1 - mx);
    float inv = 1.f / (e0 + e1);
    float p0 = e0 * inv, p1 = e1 * inv;
    out[0] = l0; out[1] = l1;
    out[2] = p0; out[3] = p1;
    out[4] = (l1 > l0) ? 1.0f : 0.0f;
    out[65541] = p0; out[65542] = p1;
  }
}

extern "C" void kernel_launch(void* const* d_in, const int* in_sizes, int n_in,
                              void* d_out, int out_size, void* d_ws, size_t ws_size,
                              hipStream_t stream) {
  const float* h      = (const float*)d_in[0];
  const int*   coords = (const int*)d_in[1];
  const float* eps    = (const float*)d_in[2];
  const float* W1     = (const float*)d_in[3];
  const float* b1     = (const float*)d_in[4];
  const float* W2a    = (const float*)d_in[5];
  const float* b2a    = (const float*)d_in[6];
  const float* W2b    = (const float*)d_in[7];
  const float* b2b    = (const float*)d_in[8];
  const float* W3     = (const float*)d_in[9];
  const float* b3     = (const float*)d_in[10];
  const float* Wc     = (const float*)d_in[11];
  const float* bc     = (const float*)d_in[12];
  const float* kern   = (const float*)d_in[13];
  const int*   slide  = (const int*)d_in[16];
  float* out = (float*)d_out;
  char*  ws  = (char*)d_ws;

  unsigned short* xb   = (unsigned short*)(ws + XB_OFF);
  unsigned short* W1b  = (unsigned short*)(ws + W1B_OFF);
  unsigned short* W2ab = (unsigned short*)(ws + W2AB_OFF);
  unsigned short* W2bb = (unsigned short*)(ws + W2BB_OFF);
  float* mug    = (float*)(ws + MUG_OFF);
  float* lvg    = (float*)(ws + LVG_OFF);
  float* Mpart2 = (float*)(ws + MPART2_OFF);
  float* sumAp  = (float*)(ws + SUMAP_OFF);

  convert_weights<<<2048, 256, 0, stream>>>(W1, W2a, W2b, W1b, W2ab, W2bb,
                                            (float*)(ws + MUG_OFF));
  gemm1<<<782, 256, 0, stream>>>(h, W1b, b1, xb);
  gemm2<<<391, 512, 0, stream>>>(xb, W2ab, W2bb, b2a, b2b, W3, b3, coords, mug, lvg);
  patch_pass<<<392, 256, 0, stream>>>(mug, lvg, eps, kern, slide, coords, xb,
                                      out + 5, out + 65543, Mpart2, sumAp);
  finalize<<<1, 256, 0, stream>>>(Mpart2, sumAp, Wc, bc, out);
}